// Round 1
// baseline (7781.012 us; speedup 1.0000x reference)
//
#include <hip/hip_runtime.h>
#include <hip/hip_bf16.h>
#include <math.h>

#define D_ 1024
#define H_ 8
#define QLR_ 384
#define KVLR_ 256
#define NOPE_ 128
#define ROPE_ 64
#define VD_ 128
#define E_ 8
#define INTER_ 512
#define B_ 2
#define T_ 2048
#define QKD_ 192
#define NTOK (B_*T_)

// ---------------- RMS norm (strided input slice) ----------------
__global__ __launch_bounds__(256) void rms_kernel(
    const float* __restrict__ src, int stride, int off,
    const float* __restrict__ w, float* __restrict__ out,
    int D, int outStride) {
  int row = blockIdx.x;
  const float* xr = src + (size_t)row * stride + off;
  float ss = 0.f;
  for (int i = threadIdx.x; i < D; i += blockDim.x) { float v = xr[i]; ss += v * v; }
  for (int o = 1; o < 64; o <<= 1) ss += __shfl_xor(ss, o);
  __shared__ float red[4];
  if ((threadIdx.x & 63) == 0) red[threadIdx.x >> 6] = ss;
  __syncthreads();
  float tot = red[0] + red[1] + red[2] + red[3];
  float inv = 1.f / sqrtf(tot / D + 1e-6f);
  for (int i = threadIdx.x; i < D; i += blockDim.x)
    out[(size_t)row * outStride + i] = xr[i] * inv * w[i];
}

// ---------------- fp32 tiled GEMM: C[M,N] = A[M,K] @ B[K,N] ----------------
// epilogue: optional addv (same shape as C), optional per-row scale, optional accumulate
#define BM 64
#define BN 64
#define BKT 16
#define LDT 68
__global__ __launch_bounds__(256) void gemm_f32(
    const float* __restrict__ A, const float* __restrict__ B, float* __restrict__ C,
    int M, int N, int K,
    const float* __restrict__ addv,
    const float* __restrict__ rowscale, int rsStride,
    int accum) {
  __shared__ float As[BKT][LDT];
  __shared__ float Bs[BKT][LDT];
  int bm = blockIdx.y * BM, bn = blockIdx.x * BN;
  int tx = threadIdx.x & 15, ty = threadIdx.x >> 4;
  float acc[4][4] = {};
  for (int k0 = 0; k0 < K; k0 += BKT) {
    for (int x = threadIdx.x; x < BM * BKT; x += 256) {
      int r = x >> 4, c = x & 15;
      int gm = bm + r, gk = k0 + c;
      As[c][r] = (gm < M && gk < K) ? A[(size_t)gm * K + gk] : 0.f;
    }
    for (int x = threadIdx.x; x < BKT * BN; x += 256) {
      int r = x >> 6, c = x & 63;
      int gk = k0 + r, gn = bn + c;
      Bs[r][c] = (gk < K && gn < N) ? B[(size_t)gk * N + gn] : 0.f;
    }
    __syncthreads();
    #pragma unroll
    for (int kk = 0; kk < BKT; ++kk) {
      float a0 = As[kk][ty * 4 + 0], a1 = As[kk][ty * 4 + 1];
      float a2 = As[kk][ty * 4 + 2], a3 = As[kk][ty * 4 + 3];
      float b0 = Bs[kk][tx * 4 + 0], b1 = Bs[kk][tx * 4 + 1];
      float b2 = Bs[kk][tx * 4 + 2], b3 = Bs[kk][tx * 4 + 3];
      acc[0][0] += a0 * b0; acc[0][1] += a0 * b1; acc[0][2] += a0 * b2; acc[0][3] += a0 * b3;
      acc[1][0] += a1 * b0; acc[1][1] += a1 * b1; acc[1][2] += a1 * b2; acc[1][3] += a1 * b3;
      acc[2][0] += a2 * b0; acc[2][1] += a2 * b1; acc[2][2] += a2 * b2; acc[2][3] += a2 * b3;
      acc[3][0] += a3 * b0; acc[3][1] += a3 * b1; acc[3][2] += a3 * b2; acc[3][3] += a3 * b3;
    }
    __syncthreads();
  }
  #pragma unroll
  for (int i = 0; i < 4; ++i) {
    int m = bm + ty * 4 + i;
    if (m >= M) continue;
    float rs = rowscale ? rowscale[(size_t)m * rsStride] : 1.f;
    #pragma unroll
    for (int j = 0; j < 4; ++j) {
      int n = bn + tx * 4 + j;
      if (n >= N) continue;
      float v = acc[i][j] * rs;
      if (addv) v += addv[(size_t)m * N + n];
      size_t idx = (size_t)m * N + n;
      if (accum) C[idx] += v; else C[idx] = v;
    }
  }
}

// ---------------- RoPE ----------------
__global__ void rope_q_kernel(float* __restrict__ q, const float* __restrict__ c_,
                              const float* __restrict__ s_) {
  int idx = blockIdx.x * blockDim.x + threadIdx.x;
  if (idx >= NTOK * H_ * (ROPE_ / 2)) return;
  int i = idx & 31;
  int h = (idx >> 5) & 7;
  int n = idx >> 8;
  int t = n & (T_ - 1);
  float c = c_[t * 32 + i], s = s_[t * 32 + i];
  float* base = q + (size_t)n * (H_ * QKD_) + h * QKD_ + NOPE_;
  float x0 = base[2 * i], x1 = base[2 * i + 1];
  base[2 * i]     = x0 * c - x1 * s;
  base[2 * i + 1] = x0 * s + x1 * c;
}

__global__ void rope_k_kernel(const float* __restrict__ lat, const float* __restrict__ c_,
                              const float* __restrict__ s_, float* __restrict__ kr) {
  int idx = blockIdx.x * blockDim.x + threadIdx.x;
  if (idx >= NTOK * 32) return;
  int i = idx & 31, n = idx >> 5;
  int t = n & (T_ - 1);
  float c = c_[t * 32 + i], s = s_[t * 32 + i];
  const float* base = lat + (size_t)n * 704 + (QLR_ + KVLR_);
  float x0 = base[2 * i], x1 = base[2 * i + 1];
  kr[(size_t)n * ROPE_ + 2 * i]     = x0 * c - x1 * s;
  kr[(size_t)n * ROPE_ + 2 * i + 1] = x0 * s + x1 * c;
}

// ---------------- Flash attention (fp32, causal) ----------------
#define TQ 32
#define TKt 16
__global__ __launch_bounds__(256) void attn_kernel(
    const float* __restrict__ q,   // [NTOK][H_][QKD_]
    const float* __restrict__ kv,  // [NTOK][H_][NOPE_+VD_]
    const float* __restrict__ kr,  // [NTOK][ROPE_]
    float* __restrict__ y) {       // [NTOK][H_*VD_]
  int bh = blockIdx.y; int b = bh >> 3, h = bh & 7;
  int q0 = blockIdx.x * TQ;
  int tid = threadIdx.x;
  int i = tid >> 3, jg = tid & 7;
  __shared__ float Qs[TQ][QKD_ + 1];
  __shared__ float Ks[TKt][QKD_ + 1];
  __shared__ float Vs[TKt][VD_ + 1];
  for (int x = tid; x < TQ * QKD_; x += 256) {
    int r = x / QKD_, c = x - r * QKD_;
    Qs[r][c] = q[((size_t)(b * T_ + q0 + r) * H_ + h) * QKD_ + c];
  }
  float m_i = -INFINITY, l_i = 0.f;
  float o[16];
  #pragma unroll
  for (int d = 0; d < 16; ++d) o[d] = 0.f;
  const float scale = 0.07216878364870322f; // 1/sqrt(192)
  int kend = q0 + TQ;
  for (int k0 = 0; k0 < kend; k0 += TKt) {
    __syncthreads();
    for (int x = tid; x < TKt * QKD_; x += 256) {
      int r = x / QKD_, c = x - r * QKD_;
      int kn = b * T_ + k0 + r;
      Ks[r][c] = (c < NOPE_) ? kv[((size_t)kn * H_ + h) * 256 + c]
                             : kr[(size_t)kn * ROPE_ + (c - NOPE_)];
    }
    for (int x = tid; x < TKt * VD_; x += 256) {
      int r = x >> 7, c = x & 127;
      int kn = b * T_ + k0 + r;
      Vs[r][c] = kv[((size_t)kn * H_ + h) * 256 + NOPE_ + c];
    }
    __syncthreads();
    float s0 = 0.f, s1 = 0.f;
    int j0 = jg * 2, j1 = jg * 2 + 1;
    for (int kk = 0; kk < QKD_; ++kk) {
      float qv = Qs[i][kk];
      s0 += qv * Ks[j0][kk];
      s1 += qv * Ks[j1][kk];
    }
    int qpos = q0 + i;
    s0 = (k0 + j0 <= qpos) ? s0 * scale : -INFINITY;
    s1 = (k0 + j1 <= qpos) ? s1 * scale : -INFINITY;
    float mt = fmaxf(s0, s1);
    for (int off = 1; off < 8; off <<= 1) mt = fmaxf(mt, __shfl_xor(mt, off));
    float m_new = fmaxf(m_i, mt);
    float p0 = expf(s0 - m_new), p1 = expf(s1 - m_new);
    float fac = expf(m_i - m_new); // first iter: exp(-inf)=0
    float ls = p0 + p1;
    for (int off = 1; off < 8; off <<= 1) ls += __shfl_xor(ls, off);
    l_i = l_i * fac + ls;
    m_i = m_new;
    #pragma unroll
    for (int d = 0; d < 16; ++d) o[d] *= fac;
    int laneBase = (tid & 63) & 56;
    #pragma unroll
    for (int g = 0; g < 8; ++g) {
      float pa = __shfl(p0, laneBase + g);
      float pb = __shfl(p1, laneBase + g);
      int ja = g * 2, jb = g * 2 + 1;
      #pragma unroll
      for (int d = 0; d < 16; ++d)
        o[d] += pa * Vs[ja][jg * 16 + d] + pb * Vs[jb][jg * 16 + d];
    }
  }
  float invl = 1.f / l_i;
  int n = b * T_ + q0 + i;
  #pragma unroll
  for (int d = 0; d < 16; ++d)
    y[(size_t)n * D_ + h * VD_ + jg * 16 + d] = o[d] * invl;
}

// ---------------- silu(a)*b, in-place into a ----------------
__global__ void silu_mul_kernel(float* __restrict__ t1, const float* __restrict__ t3, size_t n) {
  size_t idx = (size_t)blockIdx.x * blockDim.x + threadIdx.x;
  if (idx >= n) return;
  float a = t1[idx];
  t1[idx] = (a / (1.f + expf(-a))) * t3[idx];
}

// ---------------- gate: softmax over 8 + top-2 -> cw[N][8] ----------------
__global__ void gate_kernel(const float* __restrict__ logits, float* __restrict__ cw) {
  int n = blockIdx.x * blockDim.x + threadIdx.x;
  if (n >= NTOK) return;
  float v[E_]; float mx = -INFINITY;
  for (int e = 0; e < E_; ++e) { v[e] = logits[n * E_ + e]; mx = fmaxf(mx, v[e]); }
  float sum = 0.f;
  for (int e = 0; e < E_; ++e) { v[e] = expf(v[e] - mx); sum += v[e]; }
  float inv = 1.f / sum;
  int i1 = 0; float b1 = v[0];
  for (int e = 1; e < E_; ++e) if (v[e] > b1) { b1 = v[e]; i1 = e; }
  int i2 = -1; float b2 = -INFINITY;
  for (int e = 0; e < E_; ++e) if (e != i1 && v[e] > b2) { b2 = v[e]; i2 = e; }
  for (int e = 0; e < E_; ++e)
    cw[n * E_ + e] = (e == i1) ? b1 * inv : (e == i2 ? b2 * inv : 0.f);
}

extern "C" void kernel_launch(void* const* d_in, const int* in_sizes, int n_in,
                              void* d_out, int out_size, void* d_ws, size_t ws_size,
                              hipStream_t stream) {
  const float* x        = (const float*)d_in[0];
  const float* fcos     = (const float*)d_in[1];
  const float* fsin     = (const float*)d_in[2];
  const float* rmsn1_w  = (const float*)d_in[3];
  const float* rmsn2_w  = (const float*)d_in[4];
  const float* latent_w = (const float*)d_in[5];
  const float* q_norm_w = (const float*)d_in[6];
  const float* q_up_w   = (const float*)d_in[7];
  const float* kv_norm_w= (const float*)d_in[8];
  const float* kv_up_w  = (const float*)d_in[9];
  const float* c_proj_w = (const float*)d_in[10];
  const float* gate_w   = (const float*)d_in[11];
  const float* sh_w1    = (const float*)d_in[12];
  const float* sh_w2    = (const float*)d_in[13];
  const float* sh_w3    = (const float*)d_in[14];
  const float* e_w1     = (const float*)d_in[15];
  const float* e_w2     = (const float*)d_in[16];
  const float* e_w3     = (const float*)d_in[17];
  float* out = (float*)d_out;

  float* ws = (float*)d_ws;
  size_t off = 0;
  float* h   = ws + off; off += (size_t)NTOK * D_;          // reused as h2
  float* lat = ws + off; off += (size_t)NTOK * 704;
  float* qn  = ws + off; off += (size_t)NTOK * QLR_;
  float* qq  = ws + off; off += (size_t)NTOK * (H_ * QKD_); // reused as t3
  float* kvn = ws + off; off += (size_t)NTOK * KVLR_;       // reused as glog/cw
  float* kvb = ws + off; off += (size_t)NTOK * 2048;        // reused as eh1/eh3
  float* kr  = ws + off; off += (size_t)NTOK * ROPE_;
  float* y   = ws + off; off += (size_t)NTOK * D_;          // reused as t1

  float* h2   = h;
  float* t1   = y;
  float* t3   = qq;
  float* glog = kvn;
  float* cw   = kvn + (size_t)NTOK * E_;
  float* eh1  = kvb;
  float* eh3  = kvb + (size_t)NTOK * INTER_;

  dim3 blk(256);
  auto gg = [](int M, int N) { return dim3((unsigned)((N + 63) / 64), (unsigned)((M + 63) / 64)); };

  // h = rms(x)
  rms_kernel<<<NTOK, blk, 0, stream>>>(x, D_, 0, rmsn1_w, h, D_, D_);
  // lat = h @ latent_w  (4096 x 704 x 1024)
  gemm_f32<<<gg(NTOK, 704), blk, 0, stream>>>(h, latent_w, lat, NTOK, 704, D_, nullptr, nullptr, 0, 0);
  // qn = rms(lat[:, :384]) ; kvn = rms(lat[:, 384:640]) ; kr = rope(lat[:, 640:704])
  rms_kernel<<<NTOK, blk, 0, stream>>>(lat, 704, 0, q_norm_w, qn, QLR_, QLR_);
  rms_kernel<<<NTOK, blk, 0, stream>>>(lat, 704, QLR_, kv_norm_w, kvn, KVLR_, KVLR_);
  rope_k_kernel<<<(NTOK * 32 + 255) / 256, blk, 0, stream>>>(lat, fcos, fsin, kr);
  // qq = qn @ q_up_w (4096 x 1536 x 384), rope in-place
  gemm_f32<<<gg(NTOK, H_ * QKD_), blk, 0, stream>>>(qn, q_up_w, qq, NTOK, H_ * QKD_, QLR_, nullptr, nullptr, 0, 0);
  rope_q_kernel<<<(NTOK * H_ * 32 + 255) / 256, blk, 0, stream>>>(qq, fcos, fsin);
  // kvb = kvn @ kv_up_w (4096 x 2048 x 256)
  gemm_f32<<<gg(NTOK, 2048), blk, 0, stream>>>(kvn, kv_up_w, kvb, NTOK, 2048, KVLR_, nullptr, nullptr, 0, 0);
  // attention -> y
  attn_kernel<<<dim3(T_ / TQ, B_ * H_), blk, 0, stream>>>(qq, kvb, kr, y);
  // out = x + y @ c_proj_w
  gemm_f32<<<gg(NTOK, D_), blk, 0, stream>>>(y, c_proj_w, out, NTOK, D_, D_, x, nullptr, 0, 0);
  // h2 = rms(out)
  rms_kernel<<<NTOK, blk, 0, stream>>>(out, D_, 0, rmsn2_w, h2, D_, D_);
  // shared expert: out += silu(h2@w1)*(h2@w3) @ w2
  gemm_f32<<<gg(NTOK, 1024), blk, 0, stream>>>(h2, sh_w1, t1, NTOK, 1024, D_, nullptr, nullptr, 0, 0);
  gemm_f32<<<gg(NTOK, 1024), blk, 0, stream>>>(h2, sh_w3, t3, NTOK, 1024, D_, nullptr, nullptr, 0, 0);
  silu_mul_kernel<<<(int)(((size_t)NTOK * 1024 + 255) / 256), blk, 0, stream>>>(t1, t3, (size_t)NTOK * 1024);
  gemm_f32<<<gg(NTOK, D_), blk, 0, stream>>>(t1, sh_w2, out, NTOK, D_, 1024, nullptr, nullptr, 0, 1);
  // gate
  gemm_f32<<<gg(NTOK, E_), blk, 0, stream>>>(h2, gate_w, glog, NTOK, E_, D_, nullptr, nullptr, 0, 0);
  gate_kernel<<<(NTOK + 255) / 256, blk, 0, stream>>>(glog, cw);
  // experts (dense, weighted accumulate — zero weight for non-selected, exact match)
  for (int e = 0; e < E_; ++e) {
    const float* w1 = e_w1 + (size_t)e * D_ * INTER_;
    const float* w2 = e_w2 + (size_t)e * INTER_ * D_;
    const float* w3 = e_w3 + (size_t)e * D_ * INTER_;
    gemm_f32<<<gg(NTOK, INTER_), blk, 0, stream>>>(h2, w1, eh1, NTOK, INTER_, D_, nullptr, nullptr, 0, 0);
    gemm_f32<<<gg(NTOK, INTER_), blk, 0, stream>>>(h2, w3, eh3, NTOK, INTER_, D_, nullptr, nullptr, 0, 0);
    silu_mul_kernel<<<(int)(((size_t)NTOK * INTER_ + 255) / 256), blk, 0, stream>>>(eh1, eh3, (size_t)NTOK * INTER_);
    gemm_f32<<<gg(NTOK, D_), blk, 0, stream>>>(eh1, w2, out, NTOK, D_, INTER_, nullptr, cw + e, E_, 1);
  }
}

// Round 2
// 869.607 us; speedup vs baseline: 8.9477x; 8.9477x over previous
//
#include <hip/hip_runtime.h>
#include <hip/hip_bf16.h>
#include <math.h>

#define D_ 1024
#define H_ 8
#define QLR_ 384
#define KVLR_ 256
#define NOPE_ 128
#define ROPE_ 64
#define VD_ 128
#define E_ 8
#define INTER_ 512
#define B_ 2
#define T_ 2048
#define QKD_ 192
#define NTOK (B_*T_)

typedef __attribute__((ext_vector_type(8))) short short8;
typedef __attribute__((ext_vector_type(4))) float f32x4;

__device__ __forceinline__ unsigned short f2bf(float f) {
  union { float f; unsigned u; } v; v.f = f;
  return (unsigned short)((v.u + 0x7FFFu + ((v.u >> 16) & 1u)) >> 16);
}
__device__ __forceinline__ float bf2f(unsigned short h) {
  union { unsigned u; float f; } v; v.u = ((unsigned)h) << 16;
  return v.f;
}

// ---------------- transpose fp32 [R][C] -> bf16 [C][R] (batched) ----------------
__global__ __launch_bounds__(256) void transpose_f32_bf16(
    const float* __restrict__ in, unsigned short* __restrict__ out,
    int R, int C, size_t inBS, size_t outBS) {
  __shared__ float tile[32][33];
  const float* inp = in + (size_t)blockIdx.z * inBS;
  unsigned short* outp = out + (size_t)blockIdx.z * outBS;
  int c0 = blockIdx.x * 32, r0 = blockIdx.y * 32;
  int tx = threadIdx.x & 31, ty = threadIdx.x >> 5;
  #pragma unroll
  for (int i = 0; i < 4; ++i) {
    int rr = ty + i * 8;
    tile[rr][tx] = inp[(size_t)(r0 + rr) * C + c0 + tx];
  }
  __syncthreads();
  #pragma unroll
  for (int i = 0; i < 4; ++i) {
    int rr = ty + i * 8;
    outp[(size_t)(c0 + rr) * R + r0 + tx] = f2bf(tile[tx][rr]);
  }
}

// ---------------- RMS norm -> bf16 (optional fp32 side copy) ----------------
template<typename TI>
__global__ __launch_bounds__(256) void rms_to_bf16(
    const TI* __restrict__ src, int stride, int off, const float* __restrict__ w,
    unsigned short* __restrict__ out, int Dd, int outStride, float* __restrict__ outf) {
  int row = blockIdx.x;
  const TI* xr = src + (size_t)row * stride + off;
  float ss = 0.f;
  for (int i = threadIdx.x; i < Dd; i += 256) {
    float v;
    if constexpr (sizeof(TI) == 2) v = bf2f((unsigned short)xr[i]); else v = (float)xr[i];
    ss += v * v;
  }
  for (int o = 1; o < 64; o <<= 1) ss += __shfl_xor(ss, o);
  __shared__ float red[4];
  if ((threadIdx.x & 63) == 0) red[threadIdx.x >> 6] = ss;
  __syncthreads();
  float tot = red[0] + red[1] + red[2] + red[3];
  float inv = 1.f / sqrtf(tot / Dd + 1e-6f);
  for (int i = threadIdx.x; i < Dd; i += 256) {
    float v;
    if constexpr (sizeof(TI) == 2) v = bf2f((unsigned short)xr[i]); else v = (float)xr[i];
    float r = v * inv * w[i];
    out[(size_t)row * outStride + i] = f2bf(r);
    if (outf) outf[(size_t)row * outStride + i] = r;
  }
}

// ---------------- bf16 MFMA GEMM: C[M,N] = A[M,K] @ Bt[N,K]^T ----------------
// MODE 0: bf16 out.  1: f32 out = acc + addv.  2: f32 out += acc.  3: f32 out += acc*rowscale[m*8]
template<int MODE>
__global__ __launch_bounds__(256) void gemm_bf16(
    const unsigned short* __restrict__ A, const unsigned short* __restrict__ Bt,
    void* __restrict__ Cv, int M, int N, int K,
    const float* __restrict__ addv, const float* __restrict__ rowscale) {
  __shared__ __align__(16) unsigned short As[128 * 32];
  __shared__ __align__(16) unsigned short Bs[128 * 32];
  const int tid = threadIdx.x;
  const int lane = tid & 63, wave = tid >> 6;
  const int wm = wave >> 1, wn = wave & 1;
  const int bm = blockIdx.y * 128, bn = blockIdx.x * 128;
  const int r = lane & 15, g = lane >> 4;

  f32x4 acc[4][4];
  #pragma unroll
  for (int i = 0; i < 4; ++i)
    #pragma unroll
    for (int j = 0; j < 4; ++j) acc[i][j] = (f32x4)0.f;

  const char* Abase = (const char*)(A + (size_t)bm * K);
  const char* Bbase = (const char*)(Bt + (size_t)bn * K);
  char* AsB = (char*)As; char* BsB = (char*)Bs;

  for (int k0 = 0; k0 < K; k0 += 32) {
    short8 av[2], bv[2];
    #pragma unroll
    for (int it = 0; it < 2; ++it) {
      int c = tid + 256 * it;
      int row = c >> 2, kc = c & 3;
      av[it] = *(const short8*)(Abase + ((size_t)row * K + k0 + kc * 8) * 2);
      bv[it] = *(const short8*)(Bbase + ((size_t)row * K + k0 + kc * 8) * 2);
    }
    __syncthreads();
    #pragma unroll
    for (int it = 0; it < 2; ++it) {
      int c = tid + 256 * it;
      int row = c >> 2, kc = c & 3;
      int off = (row * 64 + kc * 16) ^ ((row & 3) << 4);
      *(short8*)(AsB + off) = av[it];
      *(short8*)(BsB + off) = bv[it];
    }
    __syncthreads();
    short8 af[4], bf[4];
    #pragma unroll
    for (int mi = 0; mi < 4; ++mi) {
      int row = wm * 64 + mi * 16 + r;
      af[mi] = *(const short8*)(AsB + ((row * 64 + g * 16) ^ ((row & 3) << 4)));
    }
    #pragma unroll
    for (int nj = 0; nj < 4; ++nj) {
      int rowb = wn * 64 + nj * 16 + r;
      bf[nj] = *(const short8*)(BsB + ((rowb * 64 + g * 16) ^ ((rowb & 3) << 4)));
    }
    #pragma unroll
    for (int mi = 0; mi < 4; ++mi)
      #pragma unroll
      for (int nj = 0; nj < 4; ++nj)
        acc[mi][nj] = __builtin_amdgcn_mfma_f32_16x16x32_bf16(af[mi], bf[nj], acc[mi][nj], 0, 0, 0);
  }

  const int orow0 = wm * 64 + g * 4;
  const int ocol0 = bn + wn * 64 + r;
  #pragma unroll
  for (int mi = 0; mi < 4; ++mi) {
    #pragma unroll
    for (int reg = 0; reg < 4; ++reg) {
      int mrow = bm + orow0 + mi * 16 + reg;
      size_t bas = (size_t)mrow * N + ocol0;
      if (MODE == 0) {
        unsigned short* C = (unsigned short*)Cv;
        #pragma unroll
        for (int nj = 0; nj < 4; ++nj) C[bas + nj * 16] = f2bf(acc[mi][nj][reg]);
      } else if (MODE == 1) {
        float* C = (float*)Cv;
        #pragma unroll
        for (int nj = 0; nj < 4; ++nj) C[bas + nj * 16] = acc[mi][nj][reg] + addv[bas + nj * 16];
      } else if (MODE == 2) {
        float* C = (float*)Cv;
        #pragma unroll
        for (int nj = 0; nj < 4; ++nj) C[bas + nj * 16] += acc[mi][nj][reg];
      } else {
        float rs = rowscale[(size_t)mrow * E_];
        float* C = (float*)Cv;
        #pragma unroll
        for (int nj = 0; nj < 4; ++nj) C[bas + nj * 16] += acc[mi][nj][reg] * rs;
      }
    }
  }
}

// ---------------- RoPE on bf16 ----------------
__global__ void rope_q_bf16(unsigned short* __restrict__ q, const float* __restrict__ c_,
                            const float* __restrict__ s_) {
  int idx = blockIdx.x * blockDim.x + threadIdx.x;
  if (idx >= NTOK * H_ * 32) return;
  int i = idx & 31, h = (idx >> 5) & 7, n = idx >> 8;
  int t = n & (T_ - 1);
  float c = c_[t * 32 + i], s = s_[t * 32 + i];
  unsigned short* base = q + (size_t)n * (H_ * QKD_) + h * QKD_ + NOPE_;
  float x0 = bf2f(base[2 * i]), x1 = bf2f(base[2 * i + 1]);
  base[2 * i]     = f2bf(x0 * c - x1 * s);
  base[2 * i + 1] = f2bf(x0 * s + x1 * c);
}

__global__ void rope_k_bf16(const unsigned short* __restrict__ lat, const float* __restrict__ c_,
                            const float* __restrict__ s_, unsigned short* __restrict__ kr) {
  int idx = blockIdx.x * blockDim.x + threadIdx.x;
  if (idx >= NTOK * 32) return;
  int i = idx & 31, n = idx >> 5;
  int t = n & (T_ - 1);
  float c = c_[t * 32 + i], s = s_[t * 32 + i];
  const unsigned short* base = lat + (size_t)n * 768 + (QLR_ + KVLR_);
  float x0 = bf2f(base[2 * i]), x1 = bf2f(base[2 * i + 1]);
  kr[(size_t)n * ROPE_ + 2 * i]     = f2bf(x0 * c - x1 * s);
  kr[(size_t)n * ROPE_ + 2 * i + 1] = f2bf(x0 * s + x1 * c);
}

// ---------------- MFMA flash attention ----------------
#define AQ 64
#define AK 32
__global__ __launch_bounds__(256) void attn_mfma(
    const unsigned short* __restrict__ q,   // [NTOK][H][192]
    const unsigned short* __restrict__ kv,  // [NTOK][H][256]
    const unsigned short* __restrict__ kr,  // [NTOK][64]
    unsigned short* __restrict__ y) {       // [NTOK][1024]
  __shared__ __align__(16) unsigned short Qs[AQ * 192];
  __shared__ __align__(16) unsigned short Ks[AK * 192];
  __shared__ __align__(16) unsigned short Vt[128 * 40];
  __shared__ __align__(16) unsigned short Ps[4 * 16 * 32];
  const int tid = threadIdx.x, lane = tid & 63, wave = tid >> 6;
  const int r = lane & 15, g = lane >> 4;
  const int bh = blockIdx.y, b = bh >> 3, h = bh & 7;
  const int q0 = blockIdx.x * AQ;
  const size_t bT = (size_t)b * T_;
  char* QsB = (char*)Qs; char* KsB = (char*)Ks; char* VtB = (char*)Vt; char* PsB = (char*)Ps;

  #pragma unroll
  for (int it = 0; it < 6; ++it) {
    int c = tid + it * 256;
    int row = c / 24, c8 = c % 24;
    short8 v = *(const short8*)(q + ((bT + q0 + row) * H_ + h) * 192 + c8 * 8);
    *(short8*)(QsB + ((row * 384 + c8 * 16) ^ ((row & 7) << 4))) = v;
  }

  float m_i[4], l_i[4];
  f32x4 o[8];
  #pragma unroll
  for (int i = 0; i < 4; ++i) { m_i[i] = -1e30f; l_i[i] = 0.f; }
  #pragma unroll
  for (int cb = 0; cb < 8; ++cb) o[cb] = (f32x4)0.f;

  const float scale = 0.07216878364870322f;
  const int ntiles = (q0 + AQ) / AK;
  for (int kt = 0; kt < ntiles; ++kt) {
    const int k0 = kt * AK;
    __syncthreads();
    #pragma unroll
    for (int it = 0; it < 3; ++it) {
      int c = tid + it * 256;
      int row = c / 24, c8 = c % 24;
      short8 v;
      if (c8 < 16)
        v = *(const short8*)(kv + ((bT + k0 + row) * H_ + h) * 256 + c8 * 8);
      else
        v = *(const short8*)(kr + (bT + k0 + row) * 64 + (c8 - 16) * 8);
      *(short8*)(KsB + ((row * 384 + c8 * 16) ^ ((row & 7) << 4))) = v;
    }
    #pragma unroll
    for (int it = 0; it < 2; ++it) {
      int c = tid + it * 256;
      int row = c >> 4, c8 = c & 15;
      short8 v = *(const short8*)(kv + ((bT + k0 + row) * H_ + h) * 256 + 128 + c8 * 8);
      #pragma unroll
      for (int j = 0; j < 8; ++j)
        Vt[(c8 * 8 + j) * 40 + row] = (unsigned short)v[j];
    }
    __syncthreads();

    f32x4 sf0 = (f32x4)0.f, sf1 = (f32x4)0.f;
    {
      int qrow = wave * 16 + r;
      #pragma unroll
      for (int kk = 0; kk < 6; ++kk) {
        short8 aq = *(const short8*)(QsB + ((qrow * 384 + kk * 64 + g * 16) ^ ((qrow & 7) << 4)));
        short8 b0 = *(const short8*)(KsB + ((r * 384 + kk * 64 + g * 16) ^ ((r & 7) << 4)));
        short8 b1 = *(const short8*)(KsB + (((16 + r) * 384 + kk * 64 + g * 16) ^ (((16 + r) & 7) << 4)));
        sf0 = __builtin_amdgcn_mfma_f32_16x16x32_bf16(aq, b0, sf0, 0, 0, 0);
        sf1 = __builtin_amdgcn_mfma_f32_16x16x32_bf16(aq, b1, sf1, 0, 0, 0);
      }
    }
    float fac[4];
    #pragma unroll
    for (int reg = 0; reg < 4; ++reg) {
      float s0 = sf0[reg] * scale;
      float s1 = sf1[reg] * scale;
      int qp = q0 + wave * 16 + g * 4 + reg;
      if (k0 + r > qp) s0 = -1e30f;
      if (k0 + 16 + r > qp) s1 = -1e30f;
      float mt = fmaxf(s0, s1);
      mt = fmaxf(mt, __shfl_xor(mt, 1));
      mt = fmaxf(mt, __shfl_xor(mt, 2));
      mt = fmaxf(mt, __shfl_xor(mt, 4));
      mt = fmaxf(mt, __shfl_xor(mt, 8));
      float mn = fmaxf(m_i[reg], mt);
      float e0 = __expf(s0 - mn), e1 = __expf(s1 - mn);
      float fc = __expf(m_i[reg] - mn);
      float rs = e0 + e1;
      rs += __shfl_xor(rs, 1); rs += __shfl_xor(rs, 2);
      rs += __shfl_xor(rs, 4); rs += __shfl_xor(rs, 8);
      l_i[reg] = l_i[reg] * fc + rs;
      m_i[reg] = mn;
      fac[reg] = fc;
      int prow = g * 4 + reg;
      int sw = (prow & 3) << 4;
      int pb = wave * 1024;
      *(unsigned short*)(PsB + pb + ((prow * 64 + r * 2) ^ sw)) = f2bf(e0);
      *(unsigned short*)(PsB + pb + ((prow * 64 + 32 + r * 2) ^ sw)) = f2bf(e1);
    }
    #pragma unroll
    for (int cb = 0; cb < 8; ++cb)
      #pragma unroll
      for (int reg = 0; reg < 4; ++reg) o[cb][reg] *= fac[reg];
    __syncthreads();
    short8 pa = *(const short8*)(PsB + wave * 1024 + ((r * 64 + g * 16) ^ ((r & 3) << 4)));
    #pragma unroll
    for (int cb = 0; cb < 8; ++cb) {
      int d = cb * 16 + r;
      short8 vb = *(const short8*)(VtB + d * 80 + g * 16);
      o[cb] = __builtin_amdgcn_mfma_f32_16x16x32_bf16(pa, vb, o[cb], 0, 0, 0);
    }
  }

  #pragma unroll
  for (int reg = 0; reg < 4; ++reg) {
    float inv = 1.f / l_i[reg];
    int nrow = q0 + wave * 16 + g * 4 + reg;
    size_t bas = (bT + nrow) * (size_t)D_ + h * VD_;
    #pragma unroll
    for (int cb = 0; cb < 8; ++cb)
      y[bas + cb * 16 + r] = f2bf(o[cb][reg] * inv);
  }
}

// ---------------- silu(a)*b on packed halves ----------------
__global__ void silu_mul_bf16(const unsigned short* __restrict__ in, unsigned short* __restrict__ outp,
                              int hw, size_t total8) {
  size_t idx = (size_t)blockIdx.x * blockDim.x + threadIdx.x;
  if (idx >= total8) return;
  int cpr = hw >> 3;
  size_t n = idx / cpr; int c8 = (int)(idx % cpr);
  short8 a = *(const short8*)(in + n * (size_t)(2 * hw) + c8 * 8);
  short8 b = *(const short8*)(in + n * (size_t)(2 * hw) + hw + c8 * 8);
  short8 o;
  #pragma unroll
  for (int j = 0; j < 8; ++j) {
    float x = bf2f((unsigned short)a[j]);
    float yv = bf2f((unsigned short)b[j]);
    o[j] = (short)f2bf((x / (1.f + __expf(-x))) * yv);
  }
  *(short8*)(outp + n * (size_t)hw + c8 * 8) = o;
}

// ---------------- fused gate: logits + softmax + top2 -> cw[N][8] ----------------
__global__ __launch_bounds__(256) void gate_fused(
    const float* __restrict__ h2f, const float* __restrict__ gw, float* __restrict__ cw) {
  int tok = blockIdx.x * 4 + (threadIdx.x >> 6);
  int lane = threadIdx.x & 63;
  float acc[E_] = {0, 0, 0, 0, 0, 0, 0, 0};
  const float* hr = h2f + (size_t)tok * D_ + lane * 16;
  #pragma unroll
  for (int j = 0; j < 16; ++j) {
    float hx = hr[j];
    const float* wr = gw + (size_t)(lane * 16 + j) * E_;
    #pragma unroll
    for (int e = 0; e < E_; ++e) acc[e] += hx * wr[e];
  }
  #pragma unroll
  for (int e = 0; e < E_; ++e) {
    float v = acc[e];
    v += __shfl_xor(v, 1); v += __shfl_xor(v, 2); v += __shfl_xor(v, 4);
    v += __shfl_xor(v, 8); v += __shfl_xor(v, 16); v += __shfl_xor(v, 32);
    acc[e] = v;
  }
  if (lane == 0) {
    float mx = acc[0];
    #pragma unroll
    for (int e = 1; e < E_; ++e) mx = fmaxf(mx, acc[e]);
    float sum = 0.f; float v[E_];
    #pragma unroll
    for (int e = 0; e < E_; ++e) { v[e] = __expf(acc[e] - mx); sum += v[e]; }
    float inv = 1.f / sum;
    int i1 = 0; float b1 = v[0];
    #pragma unroll
    for (int e = 1; e < E_; ++e) if (v[e] > b1) { b1 = v[e]; i1 = e; }
    int i2 = -1; float b2 = -1.f;
    #pragma unroll
    for (int e = 0; e < E_; ++e) if (e != i1 && v[e] > b2) { b2 = v[e]; i2 = e; }
    #pragma unroll
    for (int e = 0; e < E_; ++e)
      cw[(size_t)tok * E_ + e] = (e == i1) ? b1 * inv : (e == i2 ? b2 * inv : 0.f);
  }
}

extern "C" void kernel_launch(void* const* d_in, const int* in_sizes, int n_in,
                              void* d_out, int out_size, void* d_ws, size_t ws_size,
                              hipStream_t stream) {
  const float* x        = (const float*)d_in[0];
  const float* fcos     = (const float*)d_in[1];
  const float* fsin     = (const float*)d_in[2];
  const float* rmsn1_w  = (const float*)d_in[3];
  const float* rmsn2_w  = (const float*)d_in[4];
  const float* latent_w = (const float*)d_in[5];
  const float* q_norm_w = (const float*)d_in[6];
  const float* q_up_w   = (const float*)d_in[7];
  const float* kv_norm_w= (const float*)d_in[8];
  const float* kv_up_w  = (const float*)d_in[9];
  const float* c_proj_w = (const float*)d_in[10];
  const float* gate_w   = (const float*)d_in[11];
  const float* sh_w1    = (const float*)d_in[12];
  const float* sh_w2    = (const float*)d_in[13];
  const float* sh_w3    = (const float*)d_in[14];
  const float* e_w1     = (const float*)d_in[15];
  const float* e_w2     = (const float*)d_in[16];
  const float* e_w3     = (const float*)d_in[17];
  float* out = (float*)d_out;

  char* base = (char*)d_ws;
  size_t off = 0;
  auto take = [&](size_t bytes) { char* p = base + off; off += (bytes + 255) & ~(size_t)255; return p; };
  unsigned short* Wlat  = (unsigned short*)take((size_t)768 * 1024 * 2);
  unsigned short* Wqup  = (unsigned short*)take((size_t)1536 * 384 * 2);
  unsigned short* Wkv   = (unsigned short*)take((size_t)2048 * 256 * 2);
  unsigned short* Wcp   = (unsigned short*)take((size_t)1024 * 1024 * 2);
  unsigned short* Wsh13 = (unsigned short*)take((size_t)2048 * 1024 * 2);
  unsigned short* Wsh2  = (unsigned short*)take((size_t)1024 * 1024 * 2);
  unsigned short* Wew13 = (unsigned short*)take((size_t)8 * 1024 * 1024 * 2);
  unsigned short* Wew2  = (unsigned short*)take((size_t)8 * 1024 * 512 * 2);
  float* cw             = (float*)take((size_t)NTOK * E_ * 4);

  size_t actStart = off;
  size_t aoff = actStart;
  auto takeA = [&](size_t bytes) { char* p = base + aoff; aoff += (bytes + 255) & ~(size_t)255; return p; };
  unsigned short* h_bf = (unsigned short*)takeA((size_t)NTOK * 1024 * 2);
  unsigned short* lat  = (unsigned short*)takeA((size_t)NTOK * 768 * 2);
  unsigned short* qn   = (unsigned short*)takeA((size_t)NTOK * 384 * 2);
  unsigned short* kvn  = (unsigned short*)takeA((size_t)NTOK * 256 * 2);
  unsigned short* qq   = (unsigned short*)takeA((size_t)NTOK * 1536 * 2);
  unsigned short* kvb  = (unsigned short*)takeA((size_t)NTOK * 2048 * 2);
  unsigned short* kr   = (unsigned short*)takeA((size_t)NTOK * 64 * 2);
  unsigned short* y    = (unsigned short*)takeA((size_t)NTOK * 1024 * 2);

  size_t coff = actStart;
  auto takeC = [&](size_t bytes) { char* p = base + coff; coff += (bytes + 255) & ~(size_t)255; return p; };
  unsigned short* h2b  = (unsigned short*)takeC((size_t)NTOK * 1024 * 2);
  unsigned short* t13  = (unsigned short*)takeC((size_t)NTOK * 2048 * 2);
  unsigned short* t1m  = (unsigned short*)takeC((size_t)NTOK * 1024 * 2);
  unsigned short* eh13 = (unsigned short*)takeC((size_t)NTOK * 1024 * 2);
  unsigned short* ehm  = (unsigned short*)takeC((size_t)NTOK * 512 * 2);
  float* h2f           = (float*)takeC((size_t)NTOK * 1024 * 4);

  dim3 blk(256);

  // --- weight conversion (transpose to [N][K] bf16) ---
  transpose_f32_bf16<<<dim3(704/32, 1024/32, 1), blk, 0, stream>>>(latent_w, Wlat, 1024, 704, 0, 0);
  transpose_f32_bf16<<<dim3(1536/32, 384/32, 1), blk, 0, stream>>>(q_up_w, Wqup, 384, 1536, 0, 0);
  transpose_f32_bf16<<<dim3(2048/32, 256/32, 1), blk, 0, stream>>>(kv_up_w, Wkv, 256, 2048, 0, 0);
  transpose_f32_bf16<<<dim3(32, 32, 1), blk, 0, stream>>>(c_proj_w, Wcp, 1024, 1024, 0, 0);
  transpose_f32_bf16<<<dim3(32, 32, 1), blk, 0, stream>>>(sh_w1, Wsh13, 1024, 1024, 0, 0);
  transpose_f32_bf16<<<dim3(32, 32, 1), blk, 0, stream>>>(sh_w3, Wsh13 + (size_t)1024 * 1024, 1024, 1024, 0, 0);
  transpose_f32_bf16<<<dim3(32, 32, 1), blk, 0, stream>>>(sh_w2, Wsh2, 1024, 1024, 0, 0);
  transpose_f32_bf16<<<dim3(512/32, 1024/32, 8), blk, 0, stream>>>(e_w1, Wew13, 1024, 512,
      (size_t)1024 * 512, (size_t)1024 * 1024);
  transpose_f32_bf16<<<dim3(512/32, 1024/32, 8), blk, 0, stream>>>(e_w3, Wew13 + (size_t)512 * 1024, 1024, 512,
      (size_t)1024 * 512, (size_t)1024 * 1024);
  transpose_f32_bf16<<<dim3(1024/32, 512/32, 8), blk, 0, stream>>>(e_w2, Wew2, 512, 1024,
      (size_t)512 * 1024, (size_t)1024 * 512);

  // --- h = rms(x) ---
  rms_to_bf16<float><<<NTOK, blk, 0, stream>>>(x, D_, 0, rmsn1_w, h_bf, D_, D_, nullptr);
  // --- lat = h @ latent_w  (N padded 704->768; junk cols unread) ---
  gemm_bf16<0><<<dim3(768/128, NTOK/128), blk, 0, stream>>>(h_bf, Wlat, lat, NTOK, 768, 1024, nullptr, nullptr);
  // --- norms + rope_k ---
  rms_to_bf16<unsigned short><<<NTOK, blk, 0, stream>>>(lat, 768, 0, q_norm_w, qn, QLR_, QLR_, nullptr);
  rms_to_bf16<unsigned short><<<NTOK, blk, 0, stream>>>(lat, 768, QLR_, kv_norm_w, kvn, KVLR_, KVLR_, nullptr);
  rope_k_bf16<<<(NTOK * 32 + 255) / 256, blk, 0, stream>>>(lat, fcos, fsin, kr);
  // --- q = rms(q_l) @ q_up ; rope ---
  gemm_bf16<0><<<dim3(1536/128, NTOK/128), blk, 0, stream>>>(qn, Wqup, qq, NTOK, 1536, 384, nullptr, nullptr);
  rope_q_bf16<<<(NTOK * H_ * 32 + 255) / 256, blk, 0, stream>>>(qq, fcos, fsin);
  // --- kv = rms(kv_l) @ kv_up ---
  gemm_bf16<0><<<dim3(2048/128, NTOK/128), blk, 0, stream>>>(kvn, Wkv, kvb, NTOK, 2048, 256, nullptr, nullptr);
  // --- attention ---
  attn_mfma<<<dim3(T_ / AQ, B_ * H_), blk, 0, stream>>>(qq, kvb, kr, y);
  // --- out = x + y @ c_proj ---
  gemm_bf16<1><<<dim3(1024/128, NTOK/128), blk, 0, stream>>>(y, Wcp, out, NTOK, 1024, 1024, x, nullptr);
  // --- h2 = rms(out) (bf16 + fp32 copy for gate) ---
  rms_to_bf16<float><<<NTOK, blk, 0, stream>>>(out, D_, 0, rmsn2_w, h2b, D_, D_, h2f);
  gate_fused<<<NTOK / 4, blk, 0, stream>>>(h2f, gate_w, cw);
  // --- shared expert ---
  gemm_bf16<0><<<dim3(2048/128, NTOK/128), blk, 0, stream>>>(h2b, Wsh13, t13, NTOK, 2048, 1024, nullptr, nullptr);
  silu_mul_bf16<<<(unsigned)(((size_t)NTOK * 1024 / 8 + 255) / 256), blk, 0, stream>>>(t13, t1m, 1024, (size_t)NTOK * 1024 / 8);
  gemm_bf16<2><<<dim3(1024/128, NTOK/128), blk, 0, stream>>>(t1m, Wsh2, out, NTOK, 1024, 1024, nullptr, nullptr);
  // --- experts (dense, weighted accumulate) ---
  for (int e = 0; e < E_; ++e) {
    gemm_bf16<0><<<dim3(1024/128, NTOK/128), blk, 0, stream>>>(h2b, Wew13 + (size_t)e * 1024 * 1024, eh13,
        NTOK, 1024, 1024, nullptr, nullptr);
    silu_mul_bf16<<<(unsigned)(((size_t)NTOK * 512 / 8 + 255) / 256), blk, 0, stream>>>(eh13, ehm, 512, (size_t)NTOK * 512 / 8);
    gemm_bf16<3><<<dim3(1024/128, NTOK/128), blk, 0, stream>>>(ehm, Wew2 + (size_t)e * 1024 * 512, out,
        NTOK, 1024, 512, nullptr, cw + e);
  }
}

// Round 3
// 484.269 us; speedup vs baseline: 16.0675x; 1.7957x over previous
//
#include <hip/hip_runtime.h>
#include <hip/hip_bf16.h>
#include <math.h>

#define D_ 1024
#define H_ 8
#define QLR_ 384
#define KVLR_ 256
#define NOPE_ 128
#define ROPE_ 64
#define VD_ 128
#define E_ 8
#define INTER_ 512
#define B_ 2
#define T_ 2048
#define QKD_ 192
#define NTOK (B_*T_)
#define LSTR 4608   // per-expert list stride
#define MAXMB 72    // max padded m-blocks across experts

typedef __attribute__((ext_vector_type(8))) short short8;
typedef __attribute__((ext_vector_type(4))) float f32x4;

__device__ __forceinline__ unsigned short f2bf(float f) {
  union { float f; unsigned u; } v; v.f = f;
  return (unsigned short)((v.u + 0x7FFFu + ((v.u >> 16) & 1u)) >> 16);
}
__device__ __forceinline__ float bf2f(unsigned short h) {
  union { unsigned u; float f; } v; v.u = ((unsigned)h) << 16;
  return v.f;
}

#define GLD16(SRC, DST) __builtin_amdgcn_global_load_lds( \
    (__attribute__((address_space(1))) void*)(SRC), \
    (__attribute__((address_space(3))) void*)(DST), 16, 0, 0)

// ---------------- transpose fp32 [R][C] -> bf16 [C][R] (batched) ----------------
__global__ __launch_bounds__(256) void transpose_f32_bf16(
    const float* __restrict__ in, unsigned short* __restrict__ out,
    int R, int C, size_t inBS, size_t outBS) {
  __shared__ float tile[32][33];
  const float* inp = in + (size_t)blockIdx.z * inBS;
  unsigned short* outp = out + (size_t)blockIdx.z * outBS;
  int c0 = blockIdx.x * 32, r0 = blockIdx.y * 32;
  int tx = threadIdx.x & 31, ty = threadIdx.x >> 5;
  #pragma unroll
  for (int i = 0; i < 4; ++i) {
    int rr = ty + i * 8;
    tile[rr][tx] = inp[(size_t)(r0 + rr) * C + c0 + tx];
  }
  __syncthreads();
  #pragma unroll
  for (int i = 0; i < 4; ++i) {
    int rr = ty + i * 8;
    outp[(size_t)(c0 + rr) * R + r0 + tx] = f2bf(tile[tx][rr]);
  }
}

// ---------------- RMS norm -> bf16 ----------------
template<typename TI>
__global__ __launch_bounds__(256) void rms_to_bf16(
    const TI* __restrict__ src, int stride, int off, const float* __restrict__ w,
    unsigned short* __restrict__ out, int Dd, int outStride) {
  int row = blockIdx.x;
  const TI* xr = src + (size_t)row * stride + off;
  float ss = 0.f;
  for (int i = threadIdx.x; i < Dd; i += 256) {
    float v;
    if constexpr (sizeof(TI) == 2) v = bf2f((unsigned short)xr[i]); else v = (float)xr[i];
    ss += v * v;
  }
  for (int o = 1; o < 64; o <<= 1) ss += __shfl_xor(ss, o);
  __shared__ float red[4];
  if ((threadIdx.x & 63) == 0) red[threadIdx.x >> 6] = ss;
  __syncthreads();
  float tot = red[0] + red[1] + red[2] + red[3];
  float inv = 1.f / sqrtf(tot / Dd + 1e-6f);
  for (int i = threadIdx.x; i < Dd; i += 256) {
    float v;
    if constexpr (sizeof(TI) == 2) v = bf2f((unsigned short)xr[i]); else v = (float)xr[i];
    out[(size_t)row * outStride + i] = f2bf(v * inv * w[i]);
  }
}

// ---------------- bf16 MFMA GEMM (m97 structure): C[M,N] = A[M,K] @ Bt[N,K]^T ----------------
// MODE 0: bf16 out.  1: f32 out = acc + addv.  2: f32 out += acc.
template<int MODE>
__global__ __launch_bounds__(256) void gemm_bf16(
    const unsigned short* __restrict__ A, const unsigned short* __restrict__ Bt,
    void* __restrict__ Cv, int M, int N, int K,
    const float* __restrict__ addv) {
  __shared__ __align__(16) unsigned short As[128 * 32];
  __shared__ __align__(16) unsigned short Bs[128 * 32];
  const int tid = threadIdx.x;
  const int lane = tid & 63, wave = tid >> 6;
  const int wm = wave >> 1, wn = wave & 1;
  const int bm = blockIdx.y * 128, bn = blockIdx.x * 128;
  const int r = lane & 15, g = lane >> 4;

  f32x4 acc[4][4];
  #pragma unroll
  for (int i = 0; i < 4; ++i)
    #pragma unroll
    for (int j = 0; j < 4; ++j) acc[i][j] = (f32x4)0.f;

  const int rl0 = wave * 16 + (lane >> 2);
  const int rl1 = rl0 + 64;
  const int kc = (lane & 3) * 8;
  char* AsB = (char*)As; char* BsB = (char*)Bs;

  for (int k0 = 0; k0 < K; k0 += 32) {
    GLD16(A + (size_t)(bm + rl0) * K + k0 + kc, AsB + wave * 1024);
    GLD16(A + (size_t)(bm + rl1) * K + k0 + kc, AsB + (wave + 4) * 1024);
    GLD16(Bt + (size_t)(bn + rl0) * K + k0 + kc, BsB + wave * 1024);
    GLD16(Bt + (size_t)(bn + rl1) * K + k0 + kc, BsB + (wave + 4) * 1024);
    __syncthreads();
    short8 af[4], bfr[4];
    #pragma unroll
    for (int mi = 0; mi < 4; ++mi)
      af[mi] = *(const short8*)(As + (wm * 64 + mi * 16 + r) * 32 + g * 8);
    #pragma unroll
    for (int nj = 0; nj < 4; ++nj)
      bfr[nj] = *(const short8*)(Bs + (wn * 64 + nj * 16 + r) * 32 + g * 8);
    #pragma unroll
    for (int mi = 0; mi < 4; ++mi)
      #pragma unroll
      for (int nj = 0; nj < 4; ++nj)
        acc[mi][nj] = __builtin_amdgcn_mfma_f32_16x16x32_bf16(af[mi], bfr[nj], acc[mi][nj], 0, 0, 0);
    __syncthreads();
  }

  const int orow0 = wm * 64 + g * 4;
  const int ocol0 = bn + wn * 64 + r;
  #pragma unroll
  for (int mi = 0; mi < 4; ++mi) {
    #pragma unroll
    for (int reg = 0; reg < 4; ++reg) {
      int mrow = bm + orow0 + mi * 16 + reg;
      size_t bas = (size_t)mrow * N + ocol0;
      if (MODE == 0) {
        unsigned short* C = (unsigned short*)Cv;
        #pragma unroll
        for (int nj = 0; nj < 4; ++nj) C[bas + nj * 16] = f2bf(acc[mi][nj][reg]);
      } else if (MODE == 1) {
        float* C = (float*)Cv;
        #pragma unroll
        for (int nj = 0; nj < 4; ++nj) C[bas + nj * 16] = acc[mi][nj][reg] + addv[bas + nj * 16];
      } else {
        float* C = (float*)Cv;
        #pragma unroll
        for (int nj = 0; nj < 4; ++nj) C[bas + nj * 16] += acc[mi][nj][reg];
      }
    }
  }
}

// ---------------- expert w13 gather GEMM: eh13[slot][1024] = h2b[tok] @ Wew13[e]^T ----------------
__global__ __launch_bounds__(256) void gemm_moe13(
    const unsigned short* __restrict__ A, const unsigned short* __restrict__ W,
    unsigned short* __restrict__ Cb,
    const int* __restrict__ lists, const int* __restrict__ map, const int* __restrict__ sbase) {
  int mb = map[blockIdx.y];
  if (mb < 0) return;
  const int e = mb >> 16, ib = mb & 0xFFFF;
  __shared__ __align__(16) unsigned short As[128 * 32];
  __shared__ __align__(16) unsigned short Bs[128 * 32];
  const int tid = threadIdx.x, lane = tid & 63, wave = tid >> 6;
  const int wm = wave >> 1, wn = wave & 1;
  const int bn = blockIdx.x * 128;
  const int r = lane & 15, g = lane >> 4;

  f32x4 acc[4][4];
  #pragma unroll
  for (int i = 0; i < 4; ++i)
    #pragma unroll
    for (int j = 0; j < 4; ++j) acc[i][j] = (f32x4)0.f;

  const int rl0 = wave * 16 + (lane >> 2), rl1 = rl0 + 64;
  const int kc = (lane & 3) * 8;
  int t0 = lists[e * LSTR + ib * 128 + rl0]; if (t0 < 0) t0 = 0;
  int t1 = lists[e * LSTR + ib * 128 + rl1]; if (t1 < 0) t1 = 0;
  const unsigned short* Wb = W + (size_t)e * 1024 * 1024;
  char* AsB = (char*)As; char* BsB = (char*)Bs;

  for (int k0 = 0; k0 < 1024; k0 += 32) {
    GLD16(A + (size_t)t0 * 1024 + k0 + kc, AsB + wave * 1024);
    GLD16(A + (size_t)t1 * 1024 + k0 + kc, AsB + (wave + 4) * 1024);
    GLD16(Wb + (size_t)(bn + rl0) * 1024 + k0 + kc, BsB + wave * 1024);
    GLD16(Wb + (size_t)(bn + rl1) * 1024 + k0 + kc, BsB + (wave + 4) * 1024);
    __syncthreads();
    short8 af[4], bfr[4];
    #pragma unroll
    for (int mi = 0; mi < 4; ++mi)
      af[mi] = *(const short8*)(As + (wm * 64 + mi * 16 + r) * 32 + g * 8);
    #pragma unroll
    for (int nj = 0; nj < 4; ++nj)
      bfr[nj] = *(const short8*)(Bs + (wn * 64 + nj * 16 + r) * 32 + g * 8);
    #pragma unroll
    for (int mi = 0; mi < 4; ++mi)
      #pragma unroll
      for (int nj = 0; nj < 4; ++nj)
        acc[mi][nj] = __builtin_amdgcn_mfma_f32_16x16x32_bf16(af[mi], bfr[nj], acc[mi][nj], 0, 0, 0);
    __syncthreads();
  }
  const int sb = sbase[e] + ib * 128;
  const int ocol0 = bn + wn * 64 + r;
  #pragma unroll
  for (int mi = 0; mi < 4; ++mi)
    #pragma unroll
    for (int reg = 0; reg < 4; ++reg) {
      int srow = sb + wm * 64 + mi * 16 + g * 4 + reg;
      #pragma unroll
      for (int nj = 0; nj < 4; ++nj)
        Cb[(size_t)srow * 1024 + ocol0 + nj * 16] = f2bf(acc[mi][nj][reg]);
    }
}

// ---------------- expert w2 GEMM + weighted atomic scatter ----------------
__global__ __launch_bounds__(256) void gemm_moe2(
    const unsigned short* __restrict__ Am, const unsigned short* __restrict__ W,
    float* __restrict__ out,
    const int* __restrict__ lists, const int* __restrict__ map, const int* __restrict__ sbase,
    const float* __restrict__ cw) {
  int mb = map[blockIdx.y];
  if (mb < 0) return;
  const int e = mb >> 16, ib = mb & 0xFFFF;
  __shared__ __align__(16) unsigned short As[128 * 32];
  __shared__ __align__(16) unsigned short Bs[128 * 32];
  const int tid = threadIdx.x, lane = tid & 63, wave = tid >> 6;
  const int wm = wave >> 1, wn = wave & 1;
  const int bn = blockIdx.x * 128;
  const int r = lane & 15, g = lane >> 4;

  f32x4 acc[4][4];
  #pragma unroll
  for (int i = 0; i < 4; ++i)
    #pragma unroll
    for (int j = 0; j < 4; ++j) acc[i][j] = (f32x4)0.f;

  const int rl0 = wave * 16 + (lane >> 2), rl1 = rl0 + 64;
  const int kc = (lane & 3) * 8;
  const int sb = sbase[e] + ib * 128;
  const unsigned short* Wb = W + (size_t)e * 512 * 1024;
  char* AsB = (char*)As; char* BsB = (char*)Bs;

  for (int k0 = 0; k0 < 512; k0 += 32) {
    GLD16(Am + (size_t)(sb + rl0) * 512 + k0 + kc, AsB + wave * 1024);
    GLD16(Am + (size_t)(sb + rl1) * 512 + k0 + kc, AsB + (wave + 4) * 1024);
    GLD16(Wb + (size_t)(bn + rl0) * 512 + k0 + kc, BsB + wave * 1024);
    GLD16(Wb + (size_t)(bn + rl1) * 512 + k0 + kc, BsB + (wave + 4) * 1024);
    __syncthreads();
    short8 af[4], bfr[4];
    #pragma unroll
    for (int mi = 0; mi < 4; ++mi)
      af[mi] = *(const short8*)(As + (wm * 64 + mi * 16 + r) * 32 + g * 8);
    #pragma unroll
    for (int nj = 0; nj < 4; ++nj)
      bfr[nj] = *(const short8*)(Bs + (wn * 64 + nj * 16 + r) * 32 + g * 8);
    #pragma unroll
    for (int mi = 0; mi < 4; ++mi)
      #pragma unroll
      for (int nj = 0; nj < 4; ++nj)
        acc[mi][nj] = __builtin_amdgcn_mfma_f32_16x16x32_bf16(af[mi], bfr[nj], acc[mi][nj], 0, 0, 0);
    __syncthreads();
  }
  const int ocol0 = bn + wn * 64 + r;
  #pragma unroll
  for (int mi = 0; mi < 4; ++mi)
    #pragma unroll
    for (int reg = 0; reg < 4; ++reg) {
      int orow = wm * 64 + mi * 16 + g * 4 + reg;
      int tok = lists[e * LSTR + ib * 128 + orow];
      if (tok >= 0) {
        float wt = cw[(size_t)tok * E_ + e];
        #pragma unroll
        for (int nj = 0; nj < 4; ++nj)
          atomicAdd(out + (size_t)tok * 1024 + ocol0 + nj * 16, acc[mi][nj][reg] * wt);
      }
    }
}

// ---------------- RoPE on bf16 ----------------
__global__ void rope_q_bf16(unsigned short* __restrict__ q, const float* __restrict__ c_,
                            const float* __restrict__ s_) {
  int idx = blockIdx.x * blockDim.x + threadIdx.x;
  if (idx >= NTOK * H_ * 32) return;
  int i = idx & 31, h = (idx >> 5) & 7, n = idx >> 8;
  int t = n & (T_ - 1);
  float c = c_[t * 32 + i], s = s_[t * 32 + i];
  unsigned short* base = q + (size_t)n * (H_ * QKD_) + h * QKD_ + NOPE_;
  float x0 = bf2f(base[2 * i]), x1 = bf2f(base[2 * i + 1]);
  base[2 * i]     = f2bf(x0 * c - x1 * s);
  base[2 * i + 1] = f2bf(x0 * s + x1 * c);
}

__global__ void rope_k_bf16(const unsigned short* __restrict__ lat, const float* __restrict__ c_,
                            const float* __restrict__ s_, unsigned short* __restrict__ kr) {
  int idx = blockIdx.x * blockDim.x + threadIdx.x;
  if (idx >= NTOK * 32) return;
  int i = idx & 31, n = idx >> 5;
  int t = n & (T_ - 1);
  float c = c_[t * 32 + i], s = s_[t * 32 + i];
  const unsigned short* base = lat + (size_t)n * 768 + (QLR_ + KVLR_);
  float x0 = bf2f(base[2 * i]), x1 = bf2f(base[2 * i + 1]);
  kr[(size_t)n * ROPE_ + 2 * i]     = f2bf(x0 * c - x1 * s);
  kr[(size_t)n * ROPE_ + 2 * i + 1] = f2bf(x0 * s + x1 * c);
}

// ---------------- V transpose: kvb V-part -> Vt[bh][128][2048] ----------------
__global__ __launch_bounds__(256) void vtrans(const unsigned short* __restrict__ kvb,
                                              unsigned short* __restrict__ vt) {
  __shared__ unsigned short tile[32][33];
  int bh = blockIdx.z; int b = bh >> 3, h = bh & 7;
  int t0 = blockIdx.x * 32, d0 = blockIdx.y * 32;
  int tx = threadIdx.x & 31, ty = threadIdx.x >> 5;
  #pragma unroll
  for (int i = 0; i < 4; ++i) {
    int row = ty + i * 8;
    tile[row][tx] = kvb[((size_t)(b * T_ + t0 + row) * H_ + h) * 256 + 128 + d0 + tx];
  }
  __syncthreads();
  #pragma unroll
  for (int i = 0; i < 4; ++i) {
    int row = ty + i * 8;
    vt[((size_t)bh * 128 + d0 + row) * T_ + t0 + tx] = tile[tx][row];
  }
}

// ---------------- MFMA flash attention (pad-pitched LDS, V pre-transposed, reg prefetch) ----------------
#define AQ 64
#define AK 32
#define QP 200
#define VP 40
__global__ __launch_bounds__(256) void attn_mfma(
    const unsigned short* __restrict__ q,   // [NTOK][H][192]
    const unsigned short* __restrict__ kv,  // [NTOK][H][256]
    const unsigned short* __restrict__ kr,  // [NTOK][64]
    const unsigned short* __restrict__ vt,  // [16][128][2048]
    unsigned short* __restrict__ y) {       // [NTOK][1024]
  __shared__ __align__(16) unsigned short Qs[AQ * QP];
  __shared__ __align__(16) unsigned short Ks[AK * QP];
  __shared__ __align__(16) unsigned short Vl[128 * VP];
  __shared__ __align__(16) unsigned short Ps[4 * 16 * VP];
  const int tid = threadIdx.x, lane = tid & 63, wave = tid >> 6;
  const int r = lane & 15, g = lane >> 4;
  const int bh = blockIdx.y, b = bh >> 3, h = bh & 7;
  const int q0 = blockIdx.x * AQ;
  const size_t bT = (size_t)b * T_;
  const unsigned short* vbase = vt + (size_t)bh * 128 * T_;

  #pragma unroll
  for (int it = 0; it < 6; ++it) {
    int c = tid + it * 256;
    int row = c / 24, c8 = c % 24;
    *(short8*)(Qs + row * QP + c8 * 8) =
        *(const short8*)(q + ((bT + q0 + row) * H_ + h) * 192 + c8 * 8);
  }

  float m_i[4], l_i[4];
  f32x4 o[8];
  #pragma unroll
  for (int i = 0; i < 4; ++i) { m_i[i] = -1e30f; l_i[i] = 0.f; }
  #pragma unroll
  for (int cb = 0; cb < 8; ++cb) o[cb] = (f32x4)0.f;

  const float scale = 0.07216878364870322f;
  const int ntiles = q0 / AK + 2;

  // prefetch tile 0
  short8 kreg[3], vreg[2];
  int krow[3], kcol[3];
  #pragma unroll
  for (int it = 0; it < 3; ++it) {
    int c = tid + it * 256;
    krow[it] = c / 24; kcol[it] = c % 24;
    kreg[it] = (kcol[it] < 16)
      ? *(const short8*)(kv + ((bT + krow[it]) * H_ + h) * 256 + kcol[it] * 8)
      : *(const short8*)(kr + (bT + krow[it]) * 64 + (kcol[it] - 16) * 8);
  }
  #pragma unroll
  for (int it = 0; it < 2; ++it) {
    int x = tid + it * 256;
    vreg[it] = *(const short8*)(vbase + (size_t)(x >> 2) * T_ + (x & 3) * 8);
  }

  for (int kt = 0; kt < ntiles; ++kt) {
    __syncthreads();
    #pragma unroll
    for (int it = 0; it < 3; ++it)
      *(short8*)(Ks + krow[it] * QP + kcol[it] * 8) = kreg[it];
    #pragma unroll
    for (int it = 0; it < 2; ++it) {
      int x = tid + it * 256;
      *(short8*)(Vl + (x >> 2) * VP + (x & 3) * 8) = vreg[it];
    }
    __syncthreads();

    if (kt + 1 < ntiles) {
      int k1 = (kt + 1) * AK;
      #pragma unroll
      for (int it = 0; it < 3; ++it)
        kreg[it] = (kcol[it] < 16)
          ? *(const short8*)(kv + ((bT + k1 + krow[it]) * H_ + h) * 256 + kcol[it] * 8)
          : *(const short8*)(kr + (bT + k1 + krow[it]) * 64 + (kcol[it] - 16) * 8);
      #pragma unroll
      for (int it = 0; it < 2; ++it) {
        int x = tid + it * 256;
        vreg[it] = *(const short8*)(vbase + (size_t)(x >> 2) * T_ + k1 + (x & 3) * 8);
      }
    }

    const int k0 = kt * AK;
    f32x4 sf0 = (f32x4)0.f, sf1 = (f32x4)0.f;
    {
      int qrow = wave * 16 + r;
      #pragma unroll
      for (int kk = 0; kk < 6; ++kk) {
        short8 aq = *(const short8*)(Qs + qrow * QP + kk * 32 + g * 8);
        short8 b0 = *(const short8*)(Ks + r * QP + kk * 32 + g * 8);
        short8 b1 = *(const short8*)(Ks + (16 + r) * QP + kk * 32 + g * 8);
        sf0 = __builtin_amdgcn_mfma_f32_16x16x32_bf16(aq, b0, sf0, 0, 0, 0);
        sf1 = __builtin_amdgcn_mfma_f32_16x16x32_bf16(aq, b1, sf1, 0, 0, 0);
      }
    }
    float fac[4];
    #pragma unroll
    for (int reg = 0; reg < 4; ++reg) {
      float s0 = sf0[reg] * scale;
      float s1 = sf1[reg] * scale;
      int qp = q0 + wave * 16 + g * 4 + reg;
      if (k0 + r > qp) s0 = -1e30f;
      if (k0 + 16 + r > qp) s1 = -1e30f;
      float mt = fmaxf(s0, s1);
      mt = fmaxf(mt, __shfl_xor(mt, 1));
      mt = fmaxf(mt, __shfl_xor(mt, 2));
      mt = fmaxf(mt, __shfl_xor(mt, 4));
      mt = fmaxf(mt, __shfl_xor(mt, 8));
      float mn = fmaxf(m_i[reg], mt);
      float e0 = __expf(s0 - mn), e1 = __expf(s1 - mn);
      float fc = __expf(m_i[reg] - mn);
      float rs = e0 + e1;
      rs += __shfl_xor(rs, 1); rs += __shfl_xor(rs, 2);
      rs += __shfl_xor(rs, 4); rs += __shfl_xor(rs, 8);
      l_i[reg] = l_i[reg] * fc + rs;
      m_i[reg] = mn;
      fac[reg] = fc;
      int prow = g * 4 + reg;
      Ps[wave * 16 * VP + prow * VP + r] = f2bf(e0);
      Ps[wave * 16 * VP + prow * VP + 16 + r] = f2bf(e1);
    }
    #pragma unroll
    for (int cb = 0; cb < 8; ++cb)
      #pragma unroll
      for (int reg = 0; reg < 4; ++reg) o[cb][reg] *= fac[reg];
    short8 pa = *(const short8*)(Ps + wave * 16 * VP + r * VP + g * 8);
    #pragma unroll
    for (int cb = 0; cb < 8; ++cb) {
      short8 vb = *(const short8*)(Vl + (cb * 16 + r) * VP + g * 8);
      o[cb] = __builtin_amdgcn_mfma_f32_16x16x32_bf16(pa, vb, o[cb], 0, 0, 0);
    }
  }

  #pragma unroll
  for (int reg = 0; reg < 4; ++reg) {
    float inv = 1.f / l_i[reg];
    int nrow = q0 + wave * 16 + g * 4 + reg;
    size_t bas = (bT + nrow) * (size_t)D_ + h * VD_;
    #pragma unroll
    for (int cb = 0; cb < 8; ++cb)
      y[bas + cb * 16 + r] = f2bf(o[cb][reg] * inv);
  }
}

// ---------------- silu(a)*b on packed halves ----------------
__global__ void silu_mul_bf16(const unsigned short* __restrict__ in, unsigned short* __restrict__ outp,
                              int hw, size_t total8) {
  size_t idx = (size_t)blockIdx.x * blockDim.x + threadIdx.x;
  if (idx >= total8) return;
  int cpr = hw >> 3;
  size_t n = idx / cpr; int c8 = (int)(idx % cpr);
  short8 a = *(const short8*)(in + n * (size_t)(2 * hw) + c8 * 8);
  short8 b = *(const short8*)(in + n * (size_t)(2 * hw) + hw + c8 * 8);
  short8 o;
  #pragma unroll
  for (int j = 0; j < 8; ++j) {
    float x = bf2f((unsigned short)a[j]);
    float yv = bf2f((unsigned short)b[j]);
    o[j] = (short)f2bf((x / (1.f + __expf(-x))) * yv);
  }
  *(short8*)(outp + n * (size_t)hw + c8 * 8) = o;
}

// ---------------- fused gate: rms + logits + softmax + top2 -> cw[N][8] ----------------
__global__ __launch_bounds__(256) void gate_fused(
    const float* __restrict__ xo, const float* __restrict__ rw,
    const float* __restrict__ gw, float* __restrict__ cw) {
  int tok = blockIdx.x * 4 + (threadIdx.x >> 6);
  int lane = threadIdx.x & 63;
  const float* hr = xo + (size_t)tok * D_ + lane * 16;
  float v[16]; float ss = 0.f;
  #pragma unroll
  for (int j = 0; j < 16; ++j) { v[j] = hr[j]; ss += v[j] * v[j]; }
  ss += __shfl_xor(ss, 1); ss += __shfl_xor(ss, 2); ss += __shfl_xor(ss, 4);
  ss += __shfl_xor(ss, 8); ss += __shfl_xor(ss, 16); ss += __shfl_xor(ss, 32);
  float inv = 1.f / sqrtf(ss / D_ + 1e-6f);
  float acc[E_] = {0, 0, 0, 0, 0, 0, 0, 0};
  #pragma unroll
  for (int j = 0; j < 16; ++j) {
    float hx = v[j] * rw[lane * 16 + j];
    const float* wr = gw + (size_t)(lane * 16 + j) * E_;
    #pragma unroll
    for (int e = 0; e < E_; ++e) acc[e] += hx * wr[e];
  }
  #pragma unroll
  for (int e = 0; e < E_; ++e) {
    float t = acc[e];
    t += __shfl_xor(t, 1); t += __shfl_xor(t, 2); t += __shfl_xor(t, 4);
    t += __shfl_xor(t, 8); t += __shfl_xor(t, 16); t += __shfl_xor(t, 32);
    acc[e] = t * inv;
  }
  if (lane == 0) {
    float mx = acc[0];
    #pragma unroll
    for (int e = 1; e < E_; ++e) mx = fmaxf(mx, acc[e]);
    float sum = 0.f; float p[E_];
    #pragma unroll
    for (int e = 0; e < E_; ++e) { p[e] = __expf(acc[e] - mx); sum += p[e]; }
    float is = 1.f / sum;
    int i1 = 0; float b1 = p[0];
    #pragma unroll
    for (int e = 1; e < E_; ++e) if (p[e] > b1) { b1 = p[e]; i1 = e; }
    int i2 = -1; float b2 = -1.f;
    #pragma unroll
    for (int e = 0; e < E_; ++e) if (e != i1 && p[e] > b2) { b2 = p[e]; i2 = e; }
    #pragma unroll
    for (int e = 0; e < E_; ++e)
      cw[(size_t)tok * E_ + e] = (e == i1) ? b1 * is : (e == i2 ? b2 * is : 0.f);
  }
}

// ---------------- MoE token compaction (deterministic) ----------------
__global__ __launch_bounds__(256) void moe_build(const float* __restrict__ cw,
                                                 int* __restrict__ lists, int* __restrict__ counts) {
  int e = blockIdx.x, tid = threadIdx.x;
  __shared__ int s[256];
  __shared__ int base;
  if (tid == 0) base = 0;
  __syncthreads();
  for (int c0 = 0; c0 < NTOK; c0 += 256) {
    int tok = c0 + tid;
    int f = (cw[(size_t)tok * E_ + e] > 0.f) ? 1 : 0;
    s[tid] = f;
    __syncthreads();
    #pragma unroll
    for (int o = 1; o < 256; o <<= 1) {
      int vv = (tid >= o) ? s[tid - o] : 0;
      __syncthreads();
      s[tid] += vv;
      __syncthreads();
    }
    if (f) lists[e * LSTR + base + s[tid] - 1] = tok;
    __syncthreads();
    if (tid == 0) base += s[255];
    __syncthreads();
  }
  int cnt = base;
  int padded = (cnt + 127) & ~127;
  for (int i2 = cnt + tid; i2 < padded; i2 += 256) lists[e * LSTR + i2] = -1;
  if (tid == 0) { counts[e] = cnt; counts[8 + e] = padded >> 7; }
}

__global__ void moe_finalize(const int* __restrict__ counts, int* __restrict__ map,
                             int* __restrict__ sbase) {
  if (threadIdx.x == 0 && blockIdx.x == 0) {
    int cum = 0;
    for (int e = 0; e < E_; ++e) {
      sbase[e] = cum * 128;
      int nb = counts[8 + e];
      for (int i = 0; i < nb; ++i) map[cum + i] = (e << 16) | i;
      cum += nb;
    }
    for (; cum < MAXMB; ++cum) map[cum] = -1;
  }
}

extern "C" void kernel_launch(void* const* d_in, const int* in_sizes, int n_in,
                              void* d_out, int out_size, void* d_ws, size_t ws_size,
                              hipStream_t stream) {
  const float* x        = (const float*)d_in[0];
  const float* fcos     = (const float*)d_in[1];
  const float* fsin     = (const float*)d_in[2];
  const float* rmsn1_w  = (const float*)d_in[3];
  const float* rmsn2_w  = (const float*)d_in[4];
  const float* latent_w = (const float*)d_in[5];
  const float* q_norm_w = (const float*)d_in[6];
  const float* q_up_w   = (const float*)d_in[7];
  const float* kv_norm_w= (const float*)d_in[8];
  const float* kv_up_w  = (const float*)d_in[9];
  const float* c_proj_w = (const float*)d_in[10];
  const float* gate_w   = (const float*)d_in[11];
  const float* sh_w1    = (const float*)d_in[12];
  const float* sh_w2    = (const float*)d_in[13];
  const float* sh_w3    = (const float*)d_in[14];
  const float* e_w1     = (const float*)d_in[15];
  const float* e_w2     = (const float*)d_in[16];
  const float* e_w3     = (const float*)d_in[17];
  float* out = (float*)d_out;

  char* base = (char*)d_ws;
  size_t off = 0;
  auto take = [&](size_t bytes) { char* p = base + off; off += (bytes + 255) & ~(size_t)255; return p; };
  unsigned short* Wlat  = (unsigned short*)take((size_t)768 * 1024 * 2);
  unsigned short* Wqup  = (unsigned short*)take((size_t)1536 * 384 * 2);
  unsigned short* Wkv   = (unsigned short*)take((size_t)2048 * 256 * 2);
  unsigned short* Wcp   = (unsigned short*)take((size_t)1024 * 1024 * 2);
  unsigned short* Wsh13 = (unsigned short*)take((size_t)2048 * 1024 * 2);
  unsigned short* Wsh2  = (unsigned short*)take((size_t)1024 * 1024 * 2);
  unsigned short* Wew13 = (unsigned short*)take((size_t)8 * 1024 * 1024 * 2);
  unsigned short* Wew2  = (unsigned short*)take((size_t)8 * 1024 * 512 * 2);
  float* cw             = (float*)take((size_t)NTOK * E_ * 4);
  int* lists            = (int*)take((size_t)E_ * LSTR * 4);
  int* counts           = (int*)take(64 * 4);
  int* map              = (int*)take(MAXMB * 4);
  int* sbase            = (int*)take(E_ * 4);
  unsigned short* Vtg   = (unsigned short*)take((size_t)16 * 128 * T_ * 2);
  unsigned short* kr    = (unsigned short*)take((size_t)NTOK * 64 * 2);

  size_t actStart = off;
  size_t aoff = actStart;
  auto takeA = [&](size_t bytes) { char* p = base + aoff; aoff += (bytes + 255) & ~(size_t)255; return p; };
  unsigned short* h_bf = (unsigned short*)takeA((size_t)NTOK * 1024 * 2);
  unsigned short* lat  = (unsigned short*)takeA((size_t)NTOK * 768 * 2);
  unsigned short* qn   = (unsigned short*)takeA((size_t)NTOK * 384 * 2);
  unsigned short* kvn  = (unsigned short*)takeA((size_t)NTOK * 256 * 2);
  unsigned short* qq   = (unsigned short*)takeA((size_t)NTOK * 1536 * 2);
  unsigned short* kvb  = (unsigned short*)takeA((size_t)NTOK * 2048 * 2);
  unsigned short* y    = (unsigned short*)takeA((size_t)NTOK * 1024 * 2);

  size_t coff = actStart;
  auto takeC = [&](size_t bytes) { char* p = base + coff; coff += (bytes + 255) & ~(size_t)255; return p; };
  unsigned short* h2b  = (unsigned short*)takeC((size_t)NTOK * 1024 * 2);
  unsigned short* t13  = (unsigned short*)takeC((size_t)NTOK * 2048 * 2);
  unsigned short* t1m  = (unsigned short*)takeC((size_t)NTOK * 1024 * 2);
  unsigned short* eh13 = (unsigned short*)takeC((size_t)9216 * 1024 * 2);
  unsigned short* ehm  = (unsigned short*)takeC((size_t)9216 * 512 * 2);

  dim3 blk(256);

  // --- weight conversion ---
  transpose_f32_bf16<<<dim3(704/32, 1024/32, 1), blk, 0, stream>>>(latent_w, Wlat, 1024, 704, 0, 0);
  transpose_f32_bf16<<<dim3(1536/32, 384/32, 1), blk, 0, stream>>>(q_up_w, Wqup, 384, 1536, 0, 0);
  transpose_f32_bf16<<<dim3(2048/32, 256/32, 1), blk, 0, stream>>>(kv_up_w, Wkv, 256, 2048, 0, 0);
  transpose_f32_bf16<<<dim3(32, 32, 1), blk, 0, stream>>>(c_proj_w, Wcp, 1024, 1024, 0, 0);
  transpose_f32_bf16<<<dim3(32, 32, 1), blk, 0, stream>>>(sh_w1, Wsh13, 1024, 1024, 0, 0);
  transpose_f32_bf16<<<dim3(32, 32, 1), blk, 0, stream>>>(sh_w3, Wsh13 + (size_t)1024 * 1024, 1024, 1024, 0, 0);
  transpose_f32_bf16<<<dim3(32, 32, 1), blk, 0, stream>>>(sh_w2, Wsh2, 1024, 1024, 0, 0);
  transpose_f32_bf16<<<dim3(512/32, 1024/32, 8), blk, 0, stream>>>(e_w1, Wew13, 1024, 512,
      (size_t)1024 * 512, (size_t)1024 * 1024);
  transpose_f32_bf16<<<dim3(512/32, 1024/32, 8), blk, 0, stream>>>(e_w3, Wew13 + (size_t)512 * 1024, 1024, 512,
      (size_t)1024 * 512, (size_t)1024 * 1024);
  transpose_f32_bf16<<<dim3(1024/32, 512/32, 8), blk, 0, stream>>>(e_w2, Wew2, 512, 1024,
      (size_t)512 * 1024, (size_t)1024 * 512);

  rms_to_bf16<float><<<NTOK, blk, 0, stream>>>(x, D_, 0, rmsn1_w, h_bf, D_, D_);
  gemm_bf16<0><<<dim3(6, 32), blk, 0, stream>>>(h_bf, Wlat, lat, NTOK, 768, 1024, nullptr);
  rms_to_bf16<unsigned short><<<NTOK, blk, 0, stream>>>(lat, 768, 0, q_norm_w, qn, QLR_, QLR_);
  rms_to_bf16<unsigned short><<<NTOK, blk, 0, stream>>>(lat, 768, QLR_, kv_norm_w, kvn, KVLR_, KVLR_);
  rope_k_bf16<<<(NTOK * 32 + 255) / 256, blk, 0, stream>>>(lat, fcos, fsin, kr);
  gemm_bf16<0><<<dim3(12, 32), blk, 0, stream>>>(qn, Wqup, qq, NTOK, 1536, 384, nullptr);
  rope_q_bf16<<<(NTOK * H_ * 32 + 255) / 256, blk, 0, stream>>>(qq, fcos, fsin);
  gemm_bf16<0><<<dim3(16, 32), blk, 0, stream>>>(kvn, Wkv, kvb, NTOK, 2048, 256, nullptr);
  vtrans<<<dim3(T_/32, 4, 16), blk, 0, stream>>>(kvb, Vtg);
  attn_mfma<<<dim3(T_ / AQ, B_ * H_), blk, 0, stream>>>(qq, kvb, kr, Vtg, y);
  gemm_bf16<1><<<dim3(8, 32), blk, 0, stream>>>(y, Wcp, out, NTOK, 1024, 1024, x);
  rms_to_bf16<float><<<NTOK, blk, 0, stream>>>(out, D_, 0, rmsn2_w, h2b, D_, D_);
  gate_fused<<<NTOK / 4, blk, 0, stream>>>(out, rmsn2_w, gate_w, cw);
  moe_build<<<E_, blk, 0, stream>>>(cw, lists, counts);
  moe_finalize<<<1, 64, 0, stream>>>(counts, map, sbase);
  // shared expert
  gemm_bf16<0><<<dim3(16, 32), blk, 0, stream>>>(h2b, Wsh13, t13, NTOK, 2048, 1024, nullptr);
  silu_mul_bf16<<<(unsigned)(((size_t)NTOK * 1024 / 8 + 255) / 256), blk, 0, stream>>>(t13, t1m, 1024, (size_t)NTOK * 1024 / 8);
  gemm_bf16<2><<<dim3(8, 32), blk, 0, stream>>>(t1m, Wsh2, out, NTOK, 1024, 1024, nullptr);
  // sparse experts
  gemm_moe13<<<dim3(8, MAXMB), blk, 0, stream>>>(h2b, Wew13, eh13, lists, map, sbase);
  silu_mul_bf16<<<(unsigned)(((size_t)9216 * 512 / 8 + 255) / 256), blk, 0, stream>>>(eh13, ehm, 512, (size_t)9216 * 512 / 8);
  gemm_moe2<<<dim3(8, MAXMB), blk, 0, stream>>>(ehm, Wew2, out, lists, map, sbase, cw);
}

// Round 4
// 410.968 us; speedup vs baseline: 18.9334x; 1.1784x over previous
//
#include <hip/hip_runtime.h>
#include <hip/hip_bf16.h>
#include <math.h>

#define D_ 1024
#define H_ 8
#define QLR_ 384
#define KVLR_ 256
#define NOPE_ 128
#define ROPE_ 64
#define VD_ 128
#define E_ 8
#define INTER_ 512
#define B_ 2
#define T_ 2048
#define QKD_ 192
#define NTOK (B_*T_)
#define LSTR 4608
#define MAXMB 72

typedef __attribute__((ext_vector_type(8))) short short8;
typedef __attribute__((ext_vector_type(4))) float f32x4;

__device__ __forceinline__ unsigned short f2bf(float f) {
  union { float f; unsigned u; } v; v.f = f;
  return (unsigned short)((v.u + 0x7FFFu + ((v.u >> 16) & 1u)) >> 16);
}
__device__ __forceinline__ float bf2f(unsigned short h) {
  union { unsigned u; float f; } v; v.u = ((unsigned)h) << 16;
  return v.f;
}

#define GLD16(SRC, DST) __builtin_amdgcn_global_load_lds( \
    (__attribute__((address_space(1))) void*)(SRC), \
    (__attribute__((address_space(3))) void*)(DST), 16, 0, 0)

// DPP cross-lane (within 16-lane row): quad_perm xor1=0xB1, xor2=0x4E, row_ror:4=0x124, row_ror:8=0x128
#define DPPF(v, ctrl) __int_as_float(__builtin_amdgcn_update_dpp(0, __float_as_int(v), ctrl, 0xF, 0xF, true))
__device__ __forceinline__ float dppmax16(float v) {
  v = fmaxf(v, DPPF(v, 0xB1));
  v = fmaxf(v, DPPF(v, 0x4E));
  v = fmaxf(v, DPPF(v, 0x124));
  v = fmaxf(v, DPPF(v, 0x128));
  return v;
}
__device__ __forceinline__ float dppsum16(float v) {
  v += DPPF(v, 0xB1);
  v += DPPF(v, 0x4E);
  v += DPPF(v, 0x124);
  v += DPPF(v, 0x128);
  return v;
}

// ---------------- transpose fp32 [R][C] -> bf16 [C][R] (batched) ----------------
__global__ __launch_bounds__(256) void transpose_f32_bf16(
    const float* __restrict__ in, unsigned short* __restrict__ out,
    int R, int C, size_t inBS, size_t outBS) {
  __shared__ float tile[32][33];
  const float* inp = in + (size_t)blockIdx.z * inBS;
  unsigned short* outp = out + (size_t)blockIdx.z * outBS;
  int c0 = blockIdx.x * 32, r0 = blockIdx.y * 32;
  int tx = threadIdx.x & 31, ty = threadIdx.x >> 5;
  #pragma unroll
  for (int i = 0; i < 4; ++i) {
    int rr = ty + i * 8;
    tile[rr][tx] = inp[(size_t)(r0 + rr) * C + c0 + tx];
  }
  __syncthreads();
  #pragma unroll
  for (int i = 0; i < 4; ++i) {
    int rr = ty + i * 8;
    outp[(size_t)(c0 + rr) * R + r0 + tx] = f2bf(tile[tx][rr]);
  }
}

// ---------------- interleaved pair transpose for w1/w3 fusion ----------------
// src [K][C1] fp32 (w1 if z even, w3 if z odd). dest row n for src col c:
// n = 32*(c>>4) + (c&15) + (isw3?16:0); out[n*K + k]
__global__ __launch_bounds__(256) void transpose_pair(
    const float* __restrict__ in1, const float* __restrict__ in3,
    unsigned short* __restrict__ out, int K, int C1, size_t inBS, size_t outBS) {
  __shared__ float tile[32][33];
  int z = blockIdx.z; int bat = z >> 1; int f = (z & 1) * 16;
  const float* src = ((z & 1) ? in3 : in1) + (size_t)bat * inBS;
  unsigned short* o = out + (size_t)bat * outBS;
  int c0 = blockIdx.x * 32, r0 = blockIdx.y * 32;
  int tx = threadIdx.x & 31, ty = threadIdx.x >> 5;
  #pragma unroll
  for (int i = 0; i < 4; ++i) {
    int rr = ty + i * 8;
    tile[rr][tx] = src[(size_t)(r0 + rr) * C1 + c0 + tx];
  }
  __syncthreads();
  #pragma unroll
  for (int i = 0; i < 4; ++i) {
    int cc = ty + i * 8;
    int c = c0 + cc;
    int n = ((c >> 4) << 5) + (c & 15) + f;
    o[(size_t)n * K + r0 + tx] = f2bf(tile[tx][cc]);
  }
}

// ---------------- RMS norm -> bf16 ----------------
template<typename TI>
__global__ __launch_bounds__(256) void rms_to_bf16(
    const TI* __restrict__ src, int stride, int off, const float* __restrict__ w,
    unsigned short* __restrict__ out, int Dd, int outStride) {
  int row = blockIdx.x;
  const TI* xr = src + (size_t)row * stride + off;
  float ss = 0.f;
  for (int i = threadIdx.x; i < Dd; i += 256) {
    float v;
    if constexpr (sizeof(TI) == 2) v = bf2f((unsigned short)xr[i]); else v = (float)xr[i];
    ss += v * v;
  }
  for (int o = 1; o < 64; o <<= 1) ss += __shfl_xor(ss, o);
  __shared__ float red[4];
  if ((threadIdx.x & 63) == 0) red[threadIdx.x >> 6] = ss;
  __syncthreads();
  float tot = red[0] + red[1] + red[2] + red[3];
  float inv = 1.f / sqrtf(tot / Dd + 1e-6f);
  for (int i = threadIdx.x; i < Dd; i += 256) {
    float v;
    if constexpr (sizeof(TI) == 2) v = bf2f((unsigned short)xr[i]); else v = (float)xr[i];
    out[(size_t)row * outStride + i] = f2bf(v * inv * w[i]);
  }
}

// ---------------- fused: q_norm + kv_norm + rope_k from lat ----------------
__global__ __launch_bounds__(256) void lat_post(
    const unsigned short* __restrict__ lat, const float* __restrict__ qw,
    const float* __restrict__ kw, const float* __restrict__ fc, const float* __restrict__ fs,
    unsigned short* __restrict__ qn, unsigned short* __restrict__ kvn,
    unsigned short* __restrict__ kr) {
  int row = blockIdx.x, tid = threadIdx.x;
  int lane = tid & 63, wv = tid >> 6;
  const unsigned short* lr = lat + (size_t)row * 768;
  float s1 = 0.f, s2 = 0.f;
  for (int i = tid; i < QLR_; i += 256) { float v = bf2f(lr[i]); s1 += v * v; }
  { float v = bf2f(lr[QLR_ + tid]); s2 = v * v; }
  for (int o = 1; o < 64; o <<= 1) { s1 += __shfl_xor(s1, o); s2 += __shfl_xor(s2, o); }
  __shared__ float red[8];
  if (lane == 0) { red[wv] = s1; red[4 + wv] = s2; }
  __syncthreads();
  float inv1 = 1.f / sqrtf((red[0] + red[1] + red[2] + red[3]) / QLR_ + 1e-6f);
  float inv2 = 1.f / sqrtf((red[4] + red[5] + red[6] + red[7]) / KVLR_ + 1e-6f);
  for (int i = tid; i < QLR_; i += 256)
    qn[(size_t)row * QLR_ + i] = f2bf(bf2f(lr[i]) * inv1 * qw[i]);
  kvn[(size_t)row * KVLR_ + tid] = f2bf(bf2f(lr[QLR_ + tid]) * inv2 * kw[tid]);
  if (tid < 32) {
    int t = row & (T_ - 1);
    float c = fc[t * 32 + tid], s = fs[t * 32 + tid];
    float x0 = bf2f(lr[640 + 2 * tid]), x1 = bf2f(lr[640 + 2 * tid + 1]);
    kr[(size_t)row * ROPE_ + 2 * tid]     = f2bf(x0 * c - x1 * s);
    kr[(size_t)row * ROPE_ + 2 * tid + 1] = f2bf(x0 * s + x1 * c);
  }
}

// ---------------- bf16 MFMA GEMM: C[M,N] = A[M,K] @ Bt[N,K]^T ----------------
// MODE 0: bf16 out. 1: f32 out = acc + addv. 2: f32 out += acc. 4: silu-pair -> bf16 [M][N/2]
template<int MODE>
__global__ __launch_bounds__(256) void gemm_bf16(
    const unsigned short* __restrict__ A, const unsigned short* __restrict__ Bt,
    void* __restrict__ Cv, int M, int N, int K,
    const float* __restrict__ addv) {
  __shared__ __align__(16) unsigned short As[128 * 32];
  __shared__ __align__(16) unsigned short Bs[128 * 32];
  const int tid = threadIdx.x;
  const int lane = tid & 63, wave = tid >> 6;
  const int wm = wave >> 1, wn = wave & 1;
  const int bm = blockIdx.y * 128, bn = blockIdx.x * 128;
  const int r = lane & 15, g = lane >> 4;

  f32x4 acc[4][4];
  #pragma unroll
  for (int i = 0; i < 4; ++i)
    #pragma unroll
    for (int j = 0; j < 4; ++j) acc[i][j] = (f32x4)0.f;

  const int rl0 = wave * 16 + (lane >> 2);
  const int rl1 = rl0 + 64;
  const int kc = (lane & 3) * 8;
  char* AsB = (char*)As; char* BsB = (char*)Bs;

  for (int k0 = 0; k0 < K; k0 += 32) {
    GLD16(A + (size_t)(bm + rl0) * K + k0 + kc, AsB + wave * 1024);
    GLD16(A + (size_t)(bm + rl1) * K + k0 + kc, AsB + (wave + 4) * 1024);
    GLD16(Bt + (size_t)(bn + rl0) * K + k0 + kc, BsB + wave * 1024);
    GLD16(Bt + (size_t)(bn + rl1) * K + k0 + kc, BsB + (wave + 4) * 1024);
    __syncthreads();
    short8 af[4], bfr[4];
    #pragma unroll
    for (int mi = 0; mi < 4; ++mi)
      af[mi] = *(const short8*)(As + (wm * 64 + mi * 16 + r) * 32 + g * 8);
    #pragma unroll
    for (int nj = 0; nj < 4; ++nj)
      bfr[nj] = *(const short8*)(Bs + (wn * 64 + nj * 16 + r) * 32 + g * 8);
    #pragma unroll
    for (int mi = 0; mi < 4; ++mi)
      #pragma unroll
      for (int nj = 0; nj < 4; ++nj)
        acc[mi][nj] = __builtin_amdgcn_mfma_f32_16x16x32_bf16(af[mi], bfr[nj], acc[mi][nj], 0, 0, 0);
    __syncthreads();
  }

  const int orow0 = wm * 64 + g * 4;
  const int ocol0 = bn + wn * 64 + r;
  #pragma unroll
  for (int mi = 0; mi < 4; ++mi) {
    #pragma unroll
    for (int reg = 0; reg < 4; ++reg) {
      int mrow = bm + orow0 + mi * 16 + reg;
      if (MODE == 4) {
        unsigned short* C = (unsigned short*)Cv;
        size_t bas2 = (size_t)mrow * (N >> 1) + ((bn + wn * 64) >> 1) + r;
        #pragma unroll
        for (int p = 0; p < 2; ++p) {
          float a = acc[mi][2 * p][reg], b3 = acc[mi][2 * p + 1][reg];
          C[bas2 + p * 16] = f2bf((a / (1.f + __expf(-a))) * b3);
        }
      } else {
        size_t bas = (size_t)mrow * N + ocol0;
        if (MODE == 0) {
          unsigned short* C = (unsigned short*)Cv;
          #pragma unroll
          for (int nj = 0; nj < 4; ++nj) C[bas + nj * 16] = f2bf(acc[mi][nj][reg]);
        } else if (MODE == 1) {
          float* C = (float*)Cv;
          #pragma unroll
          for (int nj = 0; nj < 4; ++nj) C[bas + nj * 16] = acc[mi][nj][reg] + addv[bas + nj * 16];
        } else {
          float* C = (float*)Cv;
          #pragma unroll
          for (int nj = 0; nj < 4; ++nj) C[bas + nj * 16] += acc[mi][nj][reg];
        }
      }
    }
  }
}

// ---------------- expert w13 gather GEMM + fused silu -> ehm[slot][512] ----------------
__global__ __launch_bounds__(256) void gemm_moe13(
    const unsigned short* __restrict__ A, const unsigned short* __restrict__ W,
    unsigned short* __restrict__ Cb,
    const int* __restrict__ lists, const int* __restrict__ map, const int* __restrict__ sbase) {
  int mb = map[blockIdx.y];
  if (mb < 0) return;
  const int e = mb >> 16, ib = mb & 0xFFFF;
  __shared__ __align__(16) unsigned short As[128 * 32];
  __shared__ __align__(16) unsigned short Bs[128 * 32];
  const int tid = threadIdx.x, lane = tid & 63, wave = tid >> 6;
  const int wm = wave >> 1, wn = wave & 1;
  const int bn = blockIdx.x * 128;
  const int r = lane & 15, g = lane >> 4;

  f32x4 acc[4][4];
  #pragma unroll
  for (int i = 0; i < 4; ++i)
    #pragma unroll
    for (int j = 0; j < 4; ++j) acc[i][j] = (f32x4)0.f;

  const int rl0 = wave * 16 + (lane >> 2), rl1 = rl0 + 64;
  const int kc = (lane & 3) * 8;
  int t0 = lists[e * LSTR + ib * 128 + rl0]; if (t0 < 0) t0 = 0;
  int t1 = lists[e * LSTR + ib * 128 + rl1]; if (t1 < 0) t1 = 0;
  const unsigned short* Wb = W + (size_t)e * 1024 * 1024;
  char* AsB = (char*)As; char* BsB = (char*)Bs;

  for (int k0 = 0; k0 < 1024; k0 += 32) {
    GLD16(A + (size_t)t0 * 1024 + k0 + kc, AsB + wave * 1024);
    GLD16(A + (size_t)t1 * 1024 + k0 + kc, AsB + (wave + 4) * 1024);
    GLD16(Wb + (size_t)(bn + rl0) * 1024 + k0 + kc, BsB + wave * 1024);
    GLD16(Wb + (size_t)(bn + rl1) * 1024 + k0 + kc, BsB + (wave + 4) * 1024);
    __syncthreads();
    short8 af[4], bfr[4];
    #pragma unroll
    for (int mi = 0; mi < 4; ++mi)
      af[mi] = *(const short8*)(As + (wm * 64 + mi * 16 + r) * 32 + g * 8);
    #pragma unroll
    for (int nj = 0; nj < 4; ++nj)
      bfr[nj] = *(const short8*)(Bs + (wn * 64 + nj * 16 + r) * 32 + g * 8);
    #pragma unroll
    for (int mi = 0; mi < 4; ++mi)
      #pragma unroll
      for (int nj = 0; nj < 4; ++nj)
        acc[mi][nj] = __builtin_amdgcn_mfma_f32_16x16x32_bf16(af[mi], bfr[nj], acc[mi][nj], 0, 0, 0);
    __syncthreads();
  }
  const int sb = sbase[e] + ib * 128;
  const int hc = ((bn + wn * 64) >> 1) + r;
  #pragma unroll
  for (int mi = 0; mi < 4; ++mi)
    #pragma unroll
    for (int reg = 0; reg < 4; ++reg) {
      int srow = sb + wm * 64 + mi * 16 + g * 4 + reg;
      #pragma unroll
      for (int p = 0; p < 2; ++p) {
        float a = acc[mi][2 * p][reg], b3 = acc[mi][2 * p + 1][reg];
        Cb[(size_t)srow * 512 + hc + p * 16] = f2bf((a / (1.f + __expf(-a))) * b3);
      }
    }
}

// ---------------- expert w2 GEMM + weighted atomic scatter ----------------
__global__ __launch_bounds__(256) void gemm_moe2(
    const unsigned short* __restrict__ Am, const unsigned short* __restrict__ W,
    float* __restrict__ out,
    const int* __restrict__ lists, const int* __restrict__ map, const int* __restrict__ sbase,
    const float* __restrict__ cw) {
  int mb = map[blockIdx.y];
  if (mb < 0) return;
  const int e = mb >> 16, ib = mb & 0xFFFF;
  __shared__ __align__(16) unsigned short As[128 * 32];
  __shared__ __align__(16) unsigned short Bs[128 * 32];
  const int tid = threadIdx.x, lane = tid & 63, wave = tid >> 6;
  const int wm = wave >> 1, wn = wave & 1;
  const int bn = blockIdx.x * 128;
  const int r = lane & 15, g = lane >> 4;

  f32x4 acc[4][4];
  #pragma unroll
  for (int i = 0; i < 4; ++i)
    #pragma unroll
    for (int j = 0; j < 4; ++j) acc[i][j] = (f32x4)0.f;

  const int rl0 = wave * 16 + (lane >> 2), rl1 = rl0 + 64;
  const int kc = (lane & 3) * 8;
  const int sb = sbase[e] + ib * 128;
  const unsigned short* Wb = W + (size_t)e * 512 * 1024;
  char* AsB = (char*)As; char* BsB = (char*)Bs;

  for (int k0 = 0; k0 < 512; k0 += 32) {
    GLD16(Am + (size_t)(sb + rl0) * 512 + k0 + kc, AsB + wave * 1024);
    GLD16(Am + (size_t)(sb + rl1) * 512 + k0 + kc, AsB + (wave + 4) * 1024);
    GLD16(Wb + (size_t)(bn + rl0) * 512 + k0 + kc, BsB + wave * 1024);
    GLD16(Wb + (size_t)(bn + rl1) * 512 + k0 + kc, BsB + (wave + 4) * 1024);
    __syncthreads();
    short8 af[4], bfr[4];
    #pragma unroll
    for (int mi = 0; mi < 4; ++mi)
      af[mi] = *(const short8*)(As + (wm * 64 + mi * 16 + r) * 32 + g * 8);
    #pragma unroll
    for (int nj = 0; nj < 4; ++nj)
      bfr[nj] = *(const short8*)(Bs + (wn * 64 + nj * 16 + r) * 32 + g * 8);
    #pragma unroll
    for (int mi = 0; mi < 4; ++mi)
      #pragma unroll
      for (int nj = 0; nj < 4; ++nj)
        acc[mi][nj] = __builtin_amdgcn_mfma_f32_16x16x32_bf16(af[mi], bfr[nj], acc[mi][nj], 0, 0, 0);
    __syncthreads();
  }
  const int ocol0 = bn + wn * 64 + r;
  #pragma unroll
  for (int mi = 0; mi < 4; ++mi)
    #pragma unroll
    for (int reg = 0; reg < 4; ++reg) {
      int orow = wm * 64 + mi * 16 + g * 4 + reg;
      int tok = lists[e * LSTR + ib * 128 + orow];
      if (tok >= 0) {
        float wt = cw[(size_t)tok * E_ + e];
        #pragma unroll
        for (int nj = 0; nj < 4; ++nj)
          atomicAdd(out + (size_t)tok * 1024 + ocol0 + nj * 16, acc[mi][nj][reg] * wt);
      }
    }
}

// ---------------- RoPE q ----------------
__global__ void rope_q_bf16(unsigned short* __restrict__ q, const float* __restrict__ c_,
                            const float* __restrict__ s_) {
  int idx = blockIdx.x * blockDim.x + threadIdx.x;
  if (idx >= NTOK * H_ * 32) return;
  int i = idx & 31, h = (idx >> 5) & 7, n = idx >> 8;
  int t = n & (T_ - 1);
  float c = c_[t * 32 + i], s = s_[t * 32 + i];
  unsigned short* base = q + (size_t)n * (H_ * QKD_) + h * QKD_ + NOPE_;
  float x0 = bf2f(base[2 * i]), x1 = bf2f(base[2 * i + 1]);
  base[2 * i]     = f2bf(x0 * c - x1 * s);
  base[2 * i + 1] = f2bf(x0 * s + x1 * c);
}

// ---------------- V transpose: kvb V-part -> Vt[bh][128][2048] ----------------
__global__ __launch_bounds__(256) void vtrans(const unsigned short* __restrict__ kvb,
                                              unsigned short* __restrict__ vt) {
  __shared__ unsigned short tile[32][33];
  int bh = blockIdx.z; int b = bh >> 3, h = bh & 7;
  int t0 = blockIdx.x * 32, d0 = blockIdx.y * 32;
  int tx = threadIdx.x & 31, ty = threadIdx.x >> 5;
  #pragma unroll
  for (int i = 0; i < 4; ++i) {
    int row = ty + i * 8;
    tile[row][tx] = kvb[((size_t)(b * T_ + t0 + row) * H_ + h) * 256 + 128 + d0 + tx];
  }
  __syncthreads();
  #pragma unroll
  for (int i = 0; i < 4; ++i) {
    int row = ty + i * 8;
    vt[((size_t)bh * 128 + d0 + row) * T_ + t0 + tx] = tile[tx][row];
  }
}

// ---------------- MFMA flash attention ----------------
#define AQ 64
#define AK 32
#define VP 40
__global__ __launch_bounds__(256) void attn_mfma(
    const unsigned short* __restrict__ q,   // [NTOK][H][192]
    const unsigned short* __restrict__ kv,  // [NTOK][H][256]
    const unsigned short* __restrict__ kr,  // [NTOK][64]
    const unsigned short* __restrict__ vt,  // [16][128][2048]
    unsigned short* __restrict__ y) {       // [NTOK][1024]
  __shared__ __align__(16) unsigned short Qs[AQ * 192];
  __shared__ __align__(16) unsigned short Ks[AK * 192];
  __shared__ __align__(16) unsigned short Vl[128 * VP];
  __shared__ __align__(16) unsigned short Ps[4 * 16 * VP];
  const int tid = threadIdx.x, lane = tid & 63, wave = tid >> 6;
  const int r = lane & 15, g = lane >> 4;
  const int bh = blockIdx.y, b = bh >> 3, h = bh & 7;
  const int qt = gridDim.x - 1 - blockIdx.x;   // LPT: longest blocks dispatch first
  const int q0 = qt * AQ;
  const size_t bT = (size_t)b * T_;
  const unsigned short* vbase = vt + (size_t)bh * 128 * T_;
  char* QsB = (char*)Qs; char* KsB = (char*)Ks;

  // Q staging (XOR-swizzled rows, pitch 384B)
  #pragma unroll
  for (int it = 0; it < 6; ++it) {
    int c = tid + it * 256;
    int row = c / 24, c8 = c % 24;
    short8 v = *(const short8*)(q + ((bT + q0 + row) * H_ + h) * 192 + c8 * 8);
    *(short8*)(QsB + ((row * 384 + c8 * 16) ^ ((row & 7) << 4))) = v;
  }

  float m_i[4], l_i[4];
  f32x4 o[8];
  #pragma unroll
  for (int i = 0; i < 4; ++i) { m_i[i] = -1e30f; l_i[i] = 0.f; }
  #pragma unroll
  for (int cb = 0; cb < 8; ++cb) o[cb] = (f32x4)0.f;

  const float scale = 0.07216878364870322f;
  const int ntiles = q0 / AK + 2;

  // prefetch tile 0 (K and V) into registers
  short8 kreg[3], vreg[2];
  int krow[3], kcol[3];
  #pragma unroll
  for (int it = 0; it < 3; ++it) {
    int c = tid + it * 256;
    krow[it] = c / 24; kcol[it] = c % 24;
    kreg[it] = (kcol[it] < 16)
      ? *(const short8*)(kv + ((bT + krow[it]) * H_ + h) * 256 + kcol[it] * 8)
      : *(const short8*)(kr + (bT + krow[it]) * 64 + (kcol[it] - 16) * 8);
  }
  #pragma unroll
  for (int it = 0; it < 2; ++it) {
    int x = tid + it * 256;
    vreg[it] = *(const short8*)(vbase + (size_t)(x >> 2) * T_ + (x & 3) * 8);
  }

  for (int kt = 0; kt < ntiles; ++kt) {
    __syncthreads();
    #pragma unroll
    for (int it = 0; it < 3; ++it)
      *(short8*)(KsB + ((krow[it] * 384 + kcol[it] * 16) ^ ((krow[it] & 7) << 4))) = kreg[it];
    #pragma unroll
    for (int it = 0; it < 2; ++it) {
      int x = tid + it * 256;
      *(short8*)(Vl + (x >> 2) * VP + (x & 3) * 8) = vreg[it];
    }
    __syncthreads();

    if (kt + 1 < ntiles) {
      int k1 = (kt + 1) * AK;
      #pragma unroll
      for (int it = 0; it < 3; ++it)
        kreg[it] = (kcol[it] < 16)
          ? *(const short8*)(kv + ((bT + k1 + krow[it]) * H_ + h) * 256 + kcol[it] * 8)
          : *(const short8*)(kr + (bT + k1 + krow[it]) * 64 + (kcol[it] - 16) * 8);
      #pragma unroll
      for (int it = 0; it < 2; ++it) {
        int x = tid + it * 256;
        vreg[it] = *(const short8*)(vbase + (size_t)(x >> 2) * T_ + k1 + (x & 3) * 8);
      }
    }

    const int k0 = kt * AK;
    f32x4 sf0 = (f32x4)0.f, sf1 = (f32x4)0.f;
    {
      int qrow = wave * 16 + r;
      int qsw = (qrow & 7) << 4, ksw = (r & 7) << 4;
      #pragma unroll
      for (int kk = 0; kk < 6; ++kk) {
        short8 aq = *(const short8*)(QsB + ((qrow * 384 + kk * 64 + g * 16) ^ qsw));
        short8 b0 = *(const short8*)(KsB + ((r * 384 + kk * 64 + g * 16) ^ ksw));
        short8 b1 = *(const short8*)(KsB + (((16 + r) * 384 + kk * 64 + g * 16) ^ ksw));
        sf0 = __builtin_amdgcn_mfma_f32_16x16x32_bf16(aq, b0, sf0, 0, 0, 0);
        sf1 = __builtin_amdgcn_mfma_f32_16x16x32_bf16(aq, b1, sf1, 0, 0, 0);
      }
    }
    float fac[4];
    bool needs = false;
    #pragma unroll
    for (int reg = 0; reg < 4; ++reg) {
      float s0 = sf0[reg] * scale;
      float s1 = sf1[reg] * scale;
      int qp = q0 + wave * 16 + g * 4 + reg;
      if (k0 + r > qp) s0 = -1e30f;
      if (k0 + 16 + r > qp) s1 = -1e30f;
      float mt = dppmax16(fmaxf(s0, s1));
      float fc, mn;
      if (mt > m_i[reg] + 5.f) {          // defer-max: rescale only on real growth
        mn = mt; fc = __expf(m_i[reg] - mn); m_i[reg] = mn; needs = true;
      } else { mn = m_i[reg]; fc = 1.f; }
      float e0 = __expf(s0 - mn), e1 = __expf(s1 - mn);
      float rs = dppsum16(e0 + e1);
      l_i[reg] = l_i[reg] * fc + rs;
      fac[reg] = fc;
      int prow = g * 4 + reg;
      Ps[wave * 16 * VP + prow * VP + r] = f2bf(e0);
      Ps[wave * 16 * VP + prow * VP + 16 + r] = f2bf(e1);
    }
    if (__any(needs)) {
      #pragma unroll
      for (int cb = 0; cb < 8; ++cb)
        #pragma unroll
        for (int reg = 0; reg < 4; ++reg) o[cb][reg] *= fac[reg];
    }
    short8 pa = *(const short8*)(Ps + wave * 16 * VP + r * VP + g * 8);
    #pragma unroll
    for (int cb = 0; cb < 8; ++cb) {
      short8 vb = *(const short8*)(Vl + (cb * 16 + r) * VP + g * 8);
      o[cb] = __builtin_amdgcn_mfma_f32_16x16x32_bf16(pa, vb, o[cb], 0, 0, 0);
    }
  }

  #pragma unroll
  for (int reg = 0; reg < 4; ++reg) {
    float inv = 1.f / l_i[reg];
    int nrow = q0 + wave * 16 + g * 4 + reg;
    size_t bas = (bT + nrow) * (size_t)D_ + h * VD_;
    #pragma unroll
    for (int cb = 0; cb < 8; ++cb)
      y[bas + cb * 16 + r] = f2bf(o[cb][reg] * inv);
  }
}

// ---------------- fused rms2 + gate (logits, softmax, top2) ----------------
__global__ __launch_bounds__(256) void rms2_gate(
    const float* __restrict__ xo, const float* __restrict__ rw, const float* __restrict__ gw,
    unsigned short* __restrict__ h2b, float* __restrict__ cw) {
  int row = blockIdx.x, tid = threadIdx.x;
  int lane = tid & 63, wv = tid >> 6;
  const float* xr = xo + (size_t)row * D_;
  float v[4]; float ss = 0.f;
  #pragma unroll
  for (int j = 0; j < 4; ++j) { v[j] = xr[tid + j * 256]; ss += v[j] * v[j]; }
  for (int o = 1; o < 64; o <<= 1) ss += __shfl_xor(ss, o);
  __shared__ float red[4];
  if (lane == 0) red[wv] = ss;
  __syncthreads();
  float inv = 1.f / sqrtf((red[0] + red[1] + red[2] + red[3]) / D_ + 1e-6f);
  float a[E_] = {0, 0, 0, 0, 0, 0, 0, 0};
  #pragma unroll
  for (int j = 0; j < 4; ++j) {
    int i = tid + j * 256;
    float hv = v[j] * inv * rw[i];
    h2b[(size_t)row * D_ + i] = f2bf(hv);
    const float* wr = gw + (size_t)i * E_;
    #pragma unroll
    for (int e = 0; e < E_; ++e) a[e] += hv * wr[e];
  }
  #pragma unroll
  for (int e = 0; e < E_; ++e) {
    float t = a[e];
    for (int o = 1; o < 64; o <<= 1) t += __shfl_xor(t, o);
    a[e] = t;
  }
  __shared__ float ga[4][E_];
  if (lane == 0)
    #pragma unroll
    for (int e = 0; e < E_; ++e) ga[wv][e] = a[e];
  __syncthreads();
  if (tid == 0) {
    float lg[E_];
    #pragma unroll
    for (int e = 0; e < E_; ++e) lg[e] = ga[0][e] + ga[1][e] + ga[2][e] + ga[3][e];
    float mx = lg[0];
    #pragma unroll
    for (int e = 1; e < E_; ++e) mx = fmaxf(mx, lg[e]);
    float sum = 0.f; float p[E_];
    #pragma unroll
    for (int e = 0; e < E_; ++e) { p[e] = __expf(lg[e] - mx); sum += p[e]; }
    float is = 1.f / sum;
    int i1 = 0; float b1 = p[0];
    #pragma unroll
    for (int e = 1; e < E_; ++e) if (p[e] > b1) { b1 = p[e]; i1 = e; }
    int i2 = -1; float b2 = -1.f;
    #pragma unroll
    for (int e = 0; e < E_; ++e) if (e != i1 && p[e] > b2) { b2 = p[e]; i2 = e; }
    #pragma unroll
    for (int e = 0; e < E_; ++e)
      cw[(size_t)row * E_ + e] = (e == i1) ? b1 * is : (e == i2 ? b2 * is : 0.f);
  }
}

// ---------------- MoE token compaction (ballot-based, deterministic) ----------------
__global__ __launch_bounds__(256) void moe_build(const float* __restrict__ cw,
                                                 int* __restrict__ lists, int* __restrict__ counts) {
  int e = blockIdx.x, tid = threadIdx.x;
  int lane = tid & 63, wv = tid >> 6;
  __shared__ int wsum[4];
  __shared__ int base;
  if (tid == 0) base = 0;
  __syncthreads();
  for (int c0 = 0; c0 < NTOK; c0 += 256) {
    int tok = c0 + tid;
    bool f = cw[(size_t)tok * E_ + e] > 0.f;
    unsigned long long m = __ballot(f);
    int pos = __popcll(m & ((1ull << lane) - 1ull));
    if (lane == 0) wsum[wv] = __popcll(m);
    __syncthreads();
    int woff = base;
    #pragma unroll
    for (int w = 0; w < 4; ++w) if (w < wv) woff += wsum[w];
    if (f) lists[e * LSTR + woff + pos] = tok;
    __syncthreads();
    if (tid == 0) base += wsum[0] + wsum[1] + wsum[2] + wsum[3];
    __syncthreads();
  }
  int cnt = base;
  int padded = (cnt + 127) & ~127;
  for (int i2 = cnt + tid; i2 < padded; i2 += 256) lists[e * LSTR + i2] = -1;
  if (tid == 0) { counts[e] = cnt; counts[8 + e] = padded >> 7; }
}

__global__ void moe_finalize(const int* __restrict__ counts, int* __restrict__ map,
                             int* __restrict__ sbase) {
  if (threadIdx.x == 0 && blockIdx.x == 0) {
    int cum = 0;
    for (int e = 0; e < E_; ++e) {
      sbase[e] = cum * 128;
      int nb = counts[8 + e];
      for (int i = 0; i < nb; ++i) map[cum + i] = (e << 16) | i;
      cum += nb;
    }
    for (; cum < MAXMB; ++cum) map[cum] = -1;
  }
}

extern "C" void kernel_launch(void* const* d_in, const int* in_sizes, int n_in,
                              void* d_out, int out_size, void* d_ws, size_t ws_size,
                              hipStream_t stream) {
  const float* x        = (const float*)d_in[0];
  const float* fcos     = (const float*)d_in[1];
  const float* fsin     = (const float*)d_in[2];
  const float* rmsn1_w  = (const float*)d_in[3];
  const float* rmsn2_w  = (const float*)d_in[4];
  const float* latent_w = (const float*)d_in[5];
  const float* q_norm_w = (const float*)d_in[6];
  const float* q_up_w   = (const float*)d_in[7];
  const float* kv_norm_w= (const float*)d_in[8];
  const float* kv_up_w  = (const float*)d_in[9];
  const float* c_proj_w = (const float*)d_in[10];
  const float* gate_w   = (const float*)d_in[11];
  const float* sh_w1    = (const float*)d_in[12];
  const float* sh_w2    = (const float*)d_in[13];
  const float* sh_w3    = (const float*)d_in[14];
  const float* e_w1     = (const float*)d_in[15];
  const float* e_w2     = (const float*)d_in[16];
  const float* e_w3     = (const float*)d_in[17];
  float* out = (float*)d_out;

  char* base = (char*)d_ws;
  size_t off = 0;
  auto take = [&](size_t bytes) { char* p = base + off; off += (bytes + 255) & ~(size_t)255; return p; };
  unsigned short* Wlat  = (unsigned short*)take((size_t)768 * 1024 * 2);
  unsigned short* Wqup  = (unsigned short*)take((size_t)1536 * 384 * 2);
  unsigned short* Wkv   = (unsigned short*)take((size_t)2048 * 256 * 2);
  unsigned short* Wcp   = (unsigned short*)take((size_t)1024 * 1024 * 2);
  unsigned short* Wsh13 = (unsigned short*)take((size_t)2048 * 1024 * 2);
  unsigned short* Wsh2  = (unsigned short*)take((size_t)1024 * 1024 * 2);
  unsigned short* Wew13 = (unsigned short*)take((size_t)8 * 1024 * 1024 * 2);
  unsigned short* Wew2  = (unsigned short*)take((size_t)8 * 1024 * 512 * 2);
  float* cw             = (float*)take((size_t)NTOK * E_ * 4);
  int* lists            = (int*)take((size_t)E_ * LSTR * 4);
  int* counts           = (int*)take(64 * 4);
  int* map              = (int*)take(MAXMB * 4);
  int* sbase            = (int*)take(E_ * 4);
  unsigned short* Vtg   = (unsigned short*)take((size_t)16 * 128 * T_ * 2);
  unsigned short* kr    = (unsigned short*)take((size_t)NTOK * 64 * 2);

  size_t actStart = off;
  size_t aoff = actStart;
  auto takeA = [&](size_t bytes) { char* p = base + aoff; aoff += (bytes + 255) & ~(size_t)255; return p; };
  unsigned short* h_bf = (unsigned short*)takeA((size_t)NTOK * 1024 * 2);
  unsigned short* lat  = (unsigned short*)takeA((size_t)NTOK * 768 * 2);
  unsigned short* qn   = (unsigned short*)takeA((size_t)NTOK * 384 * 2);
  unsigned short* kvn  = (unsigned short*)takeA((size_t)NTOK * 256 * 2);
  unsigned short* qq   = (unsigned short*)takeA((size_t)NTOK * 1536 * 2);
  unsigned short* kvb  = (unsigned short*)takeA((size_t)NTOK * 2048 * 2);
  unsigned short* y    = (unsigned short*)takeA((size_t)NTOK * 1024 * 2);

  size_t coff = actStart;
  auto takeC = [&](size_t bytes) { char* p = base + coff; coff += (bytes + 255) & ~(size_t)255; return p; };
  unsigned short* h2b  = (unsigned short*)takeC((size_t)NTOK * 1024 * 2);
  unsigned short* t1m  = (unsigned short*)takeC((size_t)NTOK * 1024 * 2);
  unsigned short* ehm  = (unsigned short*)takeC((size_t)9216 * 512 * 2);

  dim3 blk(256);

  // --- weight conversion ---
  transpose_f32_bf16<<<dim3(22, 32, 1), blk, 0, stream>>>(latent_w, Wlat, 1024, 704, 0, 0);
  transpose_f32_bf16<<<dim3(48, 12, 1), blk, 0, stream>>>(q_up_w, Wqup, 384, 1536, 0, 0);
  transpose_f32_bf16<<<dim3(64, 8, 1), blk, 0, stream>>>(kv_up_w, Wkv, 256, 2048, 0, 0);
  transpose_f32_bf16<<<dim3(32, 32, 1), blk, 0, stream>>>(c_proj_w, Wcp, 1024, 1024, 0, 0);
  transpose_f32_bf16<<<dim3(32, 32, 1), blk, 0, stream>>>(sh_w2, Wsh2, 1024, 1024, 0, 0);
  transpose_pair<<<dim3(32, 32, 2), blk, 0, stream>>>(sh_w1, sh_w3, Wsh13, 1024, 1024, 0, 0);
  transpose_pair<<<dim3(16, 32, 16), blk, 0, stream>>>(e_w1, e_w3, Wew13, 1024, 512,
      (size_t)1024 * 512, (size_t)1024 * 1024);
  transpose_f32_bf16<<<dim3(32, 16, 8), blk, 0, stream>>>(e_w2, Wew2, 512, 1024,
      (size_t)512 * 1024, (size_t)1024 * 512);

  rms_to_bf16<float><<<NTOK, blk, 0, stream>>>(x, D_, 0, rmsn1_w, h_bf, D_, D_);
  gemm_bf16<0><<<dim3(6, 32), blk, 0, stream>>>(h_bf, Wlat, lat, NTOK, 768, 1024, nullptr);
  lat_post<<<NTOK, blk, 0, stream>>>(lat, q_norm_w, kv_norm_w, fcos, fsin, qn, kvn, kr);
  gemm_bf16<0><<<dim3(12, 32), blk, 0, stream>>>(qn, Wqup, qq, NTOK, 1536, 384, nullptr);
  rope_q_bf16<<<(NTOK * H_ * 32 + 255) / 256, blk, 0, stream>>>(qq, fcos, fsin);
  gemm_bf16<0><<<dim3(16, 32), blk, 0, stream>>>(kvn, Wkv, kvb, NTOK, 2048, 256, nullptr);
  vtrans<<<dim3(T_/32, 4, 16), blk, 0, stream>>>(kvb, Vtg);
  attn_mfma<<<dim3(T_ / AQ, B_ * H_), blk, 0, stream>>>(qq, kvb, kr, Vtg, y);
  gemm_bf16<1><<<dim3(8, 32), blk, 0, stream>>>(y, Wcp, out, NTOK, 1024, 1024, x);
  rms2_gate<<<NTOK, blk, 0, stream>>>(out, rmsn2_w, gate_w, h2b, cw);
  moe_build<<<E_, blk, 0, stream>>>(cw, lists, counts);
  moe_finalize<<<1, 64, 0, stream>>>(counts, map, sbase);
  // shared expert (silu fused into w13 GEMM epilogue)
  gemm_bf16<4><<<dim3(16, 32), blk, 0, stream>>>(h2b, Wsh13, t1m, NTOK, 2048, 1024, nullptr);
  gemm_bf16<2><<<dim3(8, 32), blk, 0, stream>>>(t1m, Wsh2, out, NTOK, 1024, 1024, nullptr);
  // sparse experts (silu fused)
  gemm_moe13<<<dim3(8, MAXMB), blk, 0, stream>>>(h2b, Wew13, ehm, lists, map, sbase);
  gemm_moe2<<<dim3(8, MAXMB), blk, 0, stream>>>(ehm, Wew2, out, lists, map, sbase, cw);
}

// Round 6
// 410.287 us; speedup vs baseline: 18.9648x; 1.0017x over previous
//
#include <hip/hip_runtime.h>
#include <hip/hip_bf16.h>
#include <math.h>

#define D_ 1024
#define H_ 8
#define QLR_ 384
#define KVLR_ 256
#define NOPE_ 128
#define ROPE_ 64
#define VD_ 128
#define E_ 8
#define INTER_ 512
#define B_ 2
#define T_ 2048
#define QKD_ 192
#define NTOK (B_*T_)
#define LSTR 4608
#define MAXMB 72

typedef __attribute__((ext_vector_type(8))) short short8;
typedef __attribute__((ext_vector_type(4))) float f32x4;
typedef __attribute__((ext_vector_type(4))) unsigned short us4;

__device__ __forceinline__ unsigned short f2bf(float f) {
  union { float f; unsigned u; } v; v.f = f;
  return (unsigned short)((v.u + 0x7FFFu + ((v.u >> 16) & 1u)) >> 16);
}
__device__ __forceinline__ float bf2f(unsigned short h) {
  union { unsigned u; float f; } v; v.u = ((unsigned)h) << 16;
  return v.f;
}

#define GLD16(SRC, DST) __builtin_amdgcn_global_load_lds( \
    (__attribute__((address_space(1))) void*)(SRC), \
    (__attribute__((address_space(3))) void*)(DST), 16, 0, 0)

#define DPPF(v, ctrl) __int_as_float(__builtin_amdgcn_update_dpp(0, __float_as_int(v), ctrl, 0xF, 0xF, true))
__device__ __forceinline__ float dppmax16(float v) {
  v = fmaxf(v, DPPF(v, 0xB1));
  v = fmaxf(v, DPPF(v, 0x4E));
  v = fmaxf(v, DPPF(v, 0x124));
  v = fmaxf(v, DPPF(v, 0x128));
  return v;
}
__device__ __forceinline__ float dppsum16(float v) {
  v += DPPF(v, 0xB1);
  v += DPPF(v, 0x4E);
  v += DPPF(v, 0x124);
  v += DPPF(v, 0x128);
  return v;
}

// ---------------- transpose fp32 [R][C] -> bf16 [C][R] (batched) ----------------
__global__ __launch_bounds__(256) void transpose_f32_bf16(
    const float* __restrict__ in, unsigned short* __restrict__ out,
    int R, int C, size_t inBS, size_t outBS) {
  __shared__ float tile[32][33];
  const float* inp = in + (size_t)blockIdx.z * inBS;
  unsigned short* outp = out + (size_t)blockIdx.z * outBS;
  int c0 = blockIdx.x * 32, r0 = blockIdx.y * 32;
  int tx = threadIdx.x & 31, ty = threadIdx.x >> 5;
  #pragma unroll
  for (int i = 0; i < 4; ++i) {
    int rr = ty + i * 8;
    tile[rr][tx] = inp[(size_t)(r0 + rr) * C + c0 + tx];
  }
  __syncthreads();
  #pragma unroll
  for (int i = 0; i < 4; ++i) {
    int rr = ty + i * 8;
    outp[(size_t)(c0 + rr) * R + r0 + tx] = f2bf(tile[tx][rr]);
  }
}

// ---------------- interleaved pair transpose for w1/w3 fusion ----------------
__global__ __launch_bounds__(256) void transpose_pair(
    const float* __restrict__ in1, const float* __restrict__ in3,
    unsigned short* __restrict__ out, int K, int C1, size_t inBS, size_t outBS) {
  __shared__ float tile[32][33];
  int z = blockIdx.z; int bat = z >> 1; int f = (z & 1) * 16;
  const float* src = ((z & 1) ? in3 : in1) + (size_t)bat * inBS;
  unsigned short* o = out + (size_t)bat * outBS;
  int c0 = blockIdx.x * 32, r0 = blockIdx.y * 32;
  int tx = threadIdx.x & 31, ty = threadIdx.x >> 5;
  #pragma unroll
  for (int i = 0; i < 4; ++i) {
    int rr = ty + i * 8;
    tile[rr][tx] = src[(size_t)(r0 + rr) * C1 + c0 + tx];
  }
  __syncthreads();
  #pragma unroll
  for (int i = 0; i < 4; ++i) {
    int cc = ty + i * 8;
    int c = c0 + cc;
    int n = ((c >> 4) << 5) + (c & 15) + f;
    o[(size_t)n * K + r0 + tx] = f2bf(tile[tx][cc]);
  }
}

// ---------------- RMS norm -> bf16 ----------------
template<typename TI>
__global__ __launch_bounds__(256) void rms_to_bf16(
    const TI* __restrict__ src, int stride, int off, const float* __restrict__ w,
    unsigned short* __restrict__ out, int Dd, int outStride) {
  int row = blockIdx.x;
  const TI* xr = src + (size_t)row * stride + off;
  float ss = 0.f;
  for (int i = threadIdx.x; i < Dd; i += 256) {
    float v;
    if constexpr (sizeof(TI) == 2) v = bf2f((unsigned short)xr[i]); else v = (float)xr[i];
    ss += v * v;
  }
  for (int o = 1; o < 64; o <<= 1) ss += __shfl_xor(ss, o);
  __shared__ float red[4];
  if ((threadIdx.x & 63) == 0) red[threadIdx.x >> 6] = ss;
  __syncthreads();
  float tot = red[0] + red[1] + red[2] + red[3];
  float inv = 1.f / sqrtf(tot / Dd + 1e-6f);
  for (int i = threadIdx.x; i < Dd; i += 256) {
    float v;
    if constexpr (sizeof(TI) == 2) v = bf2f((unsigned short)xr[i]); else v = (float)xr[i];
    out[(size_t)row * outStride + i] = f2bf(v * inv * w[i]);
  }
}

// ---------------- fused: q_norm + kv_norm + rope_k from lat ----------------
__global__ __launch_bounds__(256) void lat_post(
    const unsigned short* __restrict__ lat, const float* __restrict__ qw,
    const float* __restrict__ kw, const float* __restrict__ fc, const float* __restrict__ fs,
    unsigned short* __restrict__ qn, unsigned short* __restrict__ kvn,
    unsigned short* __restrict__ kr) {
  int row = blockIdx.x, tid = threadIdx.x;
  int lane = tid & 63, wv = tid >> 6;
  const unsigned short* lr = lat + (size_t)row * 768;
  float s1 = 0.f, s2 = 0.f;
  for (int i = tid; i < QLR_; i += 256) { float v = bf2f(lr[i]); s1 += v * v; }
  { float v = bf2f(lr[QLR_ + tid]); s2 = v * v; }
  for (int o = 1; o < 64; o <<= 1) { s1 += __shfl_xor(s1, o); s2 += __shfl_xor(s2, o); }
  __shared__ float red[8];
  if (lane == 0) { red[wv] = s1; red[4 + wv] = s2; }
  __syncthreads();
  float inv1 = 1.f / sqrtf((red[0] + red[1] + red[2] + red[3]) / QLR_ + 1e-6f);
  float inv2 = 1.f / sqrtf((red[4] + red[5] + red[6] + red[7]) / KVLR_ + 1e-6f);
  for (int i = tid; i < QLR_; i += 256)
    qn[(size_t)row * QLR_ + i] = f2bf(bf2f(lr[i]) * inv1 * qw[i]);
  kvn[(size_t)row * KVLR_ + tid] = f2bf(bf2f(lr[QLR_ + tid]) * inv2 * kw[tid]);
  if (tid < 32) {
    int t = row & (T_ - 1);
    float c = fc[t * 32 + tid], s = fs[t * 32 + tid];
    float x0 = bf2f(lr[640 + 2 * tid]), x1 = bf2f(lr[640 + 2 * tid + 1]);
    kr[(size_t)row * ROPE_ + 2 * tid]     = f2bf(x0 * c - x1 * s);
    kr[(size_t)row * ROPE_ + 2 * tid + 1] = f2bf(x0 * s + x1 * c);
  }
}

// ---------------- bf16 MFMA GEMM: C[M,N] = A[M,K] @ Bt[N,K]^T ----------------
// MODE 0: bf16 out. 1: f32 out = acc + addv. 2: f32 out += acc.
// 4: silu-pair -> bf16 [M][N/2]. 5: kv_up special (nope->kvb, V->vt transposed)
template<int MODE>
__global__ __launch_bounds__(256) void gemm_bf16(
    const unsigned short* __restrict__ A, const unsigned short* __restrict__ Bt,
    void* __restrict__ Cv, int M, int N, int K,
    const float* __restrict__ addv, unsigned short* __restrict__ vtg) {
  __shared__ __align__(16) unsigned short As[128 * 32];
  __shared__ __align__(16) unsigned short Bs[128 * 32];
  const int tid = threadIdx.x;
  const int lane = tid & 63, wave = tid >> 6;
  const int wm = wave >> 1, wn = wave & 1;
  const int bm = blockIdx.y * 128, bn = blockIdx.x * 128;
  const int r = lane & 15, g = lane >> 4;

  f32x4 acc[4][4];
  #pragma unroll
  for (int i = 0; i < 4; ++i)
    #pragma unroll
    for (int j = 0; j < 4; ++j) acc[i][j] = (f32x4)0.f;

  const int rl0 = wave * 16 + (lane >> 2);
  const int rl1 = rl0 + 64;
  const int kc = (lane & 3) * 8;
  char* AsB = (char*)As; char* BsB = (char*)Bs;

  for (int k0 = 0; k0 < K; k0 += 32) {
    GLD16(A + (size_t)(bm + rl0) * K + k0 + kc, AsB + wave * 1024);
    GLD16(A + (size_t)(bm + rl1) * K + k0 + kc, AsB + (wave + 4) * 1024);
    GLD16(Bt + (size_t)(bn + rl0) * K + k0 + kc, BsB + wave * 1024);
    GLD16(Bt + (size_t)(bn + rl1) * K + k0 + kc, BsB + (wave + 4) * 1024);
    __syncthreads();
    short8 af[4], bfr[4];
    #pragma unroll
    for (int mi = 0; mi < 4; ++mi)
      af[mi] = *(const short8*)(As + (wm * 64 + mi * 16 + r) * 32 + g * 8);
    #pragma unroll
    for (int nj = 0; nj < 4; ++nj)
      bfr[nj] = *(const short8*)(Bs + (wn * 64 + nj * 16 + r) * 32 + g * 8);
    #pragma unroll
    for (int mi = 0; mi < 4; ++mi)
      #pragma unroll
      for (int nj = 0; nj < 4; ++nj)
        acc[mi][nj] = __builtin_amdgcn_mfma_f32_16x16x32_bf16(af[mi], bfr[nj], acc[mi][nj], 0, 0, 0);
    __syncthreads();
  }

  if (MODE == 5) {
    unsigned short* C = (unsigned short*)Cv;
    const int colbase = bn + wn * 64;
    const int b = bm >> 11;
    const int hh = colbase >> 8;
    if ((colbase & 255) < 128) {
      #pragma unroll
      for (int mi = 0; mi < 4; ++mi)
        #pragma unroll
        for (int reg = 0; reg < 4; ++reg) {
          int mrow = bm + wm * 64 + mi * 16 + g * 4 + reg;
          size_t bas = (size_t)mrow * N + colbase + r;
          #pragma unroll
          for (int nj = 0; nj < 4; ++nj) C[bas + nj * 16] = f2bf(acc[mi][nj][reg]);
        }
    } else {
      const int tl0 = (bm & 2047) + wm * 64 + g * 4;
      const int d0 = (colbase & 255) - 128 + r;
      #pragma unroll
      for (int mi = 0; mi < 4; ++mi)
        #pragma unroll
        for (int nj = 0; nj < 4; ++nj) {
          int d = d0 + nj * 16;
          us4 pk;
          #pragma unroll
          for (int reg = 0; reg < 4; ++reg) pk[reg] = f2bf(acc[mi][nj][reg]);
          *(us4*)(vtg + ((size_t)((b * 8 + hh) * 128 + d)) * 2048 + tl0 + mi * 16) = pk;
        }
    }
    return;
  }

  const int orow0 = wm * 64 + g * 4;
  const int ocol0 = bn + wn * 64 + r;
  #pragma unroll
  for (int mi = 0; mi < 4; ++mi) {
    #pragma unroll
    for (int reg = 0; reg < 4; ++reg) {
      int mrow = bm + orow0 + mi * 16 + reg;
      if (MODE == 4) {
        unsigned short* C = (unsigned short*)Cv;
        size_t bas2 = (size_t)mrow * (N >> 1) + ((bn + wn * 64) >> 1) + r;
        #pragma unroll
        for (int p = 0; p < 2; ++p) {
          float a = acc[mi][2 * p][reg], b3 = acc[mi][2 * p + 1][reg];
          C[bas2 + p * 16] = f2bf((a / (1.f + __expf(-a))) * b3);
        }
      } else {
        size_t bas = (size_t)mrow * N + ocol0;
        if (MODE == 0) {
          unsigned short* C = (unsigned short*)Cv;
          #pragma unroll
          for (int nj = 0; nj < 4; ++nj) C[bas + nj * 16] = f2bf(acc[mi][nj][reg]);
        } else if (MODE == 1) {
          float* C = (float*)Cv;
          #pragma unroll
          for (int nj = 0; nj < 4; ++nj) C[bas + nj * 16] = acc[mi][nj][reg] + addv[bas + nj * 16];
        } else {
          float* C = (float*)Cv;
          #pragma unroll
          for (int nj = 0; nj < 4; ++nj) C[bas + nj * 16] += acc[mi][nj][reg];
        }
      }
    }
  }
}

// ---------------- expert w13 gather GEMM + fused silu -> ehm[slot][512] ----------------
__global__ __launch_bounds__(256) void gemm_moe13(
    const unsigned short* __restrict__ A, const unsigned short* __restrict__ W,
    unsigned short* __restrict__ Cb,
    const int* __restrict__ lists, const int* __restrict__ map, const int* __restrict__ sbase) {
  int mb = map[blockIdx.y];
  if (mb < 0) return;
  const int e = mb >> 16, ib = mb & 0xFFFF;
  __shared__ __align__(16) unsigned short As[128 * 32];
  __shared__ __align__(16) unsigned short Bs[128 * 32];
  const int tid = threadIdx.x, lane = tid & 63, wave = tid >> 6;
  const int wm = wave >> 1, wn = wave & 1;
  const int bn = blockIdx.x * 128;
  const int r = lane & 15, g = lane >> 4;

  f32x4 acc[4][4];
  #pragma unroll
  for (int i = 0; i < 4; ++i)
    #pragma unroll
    for (int j = 0; j < 4; ++j) acc[i][j] = (f32x4)0.f;

  const int rl0 = wave * 16 + (lane >> 2), rl1 = rl0 + 64;
  const int kc = (lane & 3) * 8;
  int t0 = lists[e * LSTR + ib * 128 + rl0]; if (t0 < 0) t0 = 0;
  int t1 = lists[e * LSTR + ib * 128 + rl1]; if (t1 < 0) t1 = 0;
  const unsigned short* Wb = W + (size_t)e * 1024 * 1024;
  char* AsB = (char*)As; char* BsB = (char*)Bs;

  for (int k0 = 0; k0 < 1024; k0 += 32) {
    GLD16(A + (size_t)t0 * 1024 + k0 + kc, AsB + wave * 1024);
    GLD16(A + (size_t)t1 * 1024 + k0 + kc, AsB + (wave + 4) * 1024);
    GLD16(Wb + (size_t)(bn + rl0) * 1024 + k0 + kc, BsB + wave * 1024);
    GLD16(Wb + (size_t)(bn + rl1) * 1024 + k0 + kc, BsB + (wave + 4) * 1024);
    __syncthreads();
    short8 af[4], bfr[4];
    #pragma unroll
    for (int mi = 0; mi < 4; ++mi)
      af[mi] = *(const short8*)(As + (wm * 64 + mi * 16 + r) * 32 + g * 8);
    #pragma unroll
    for (int nj = 0; nj < 4; ++nj)
      bfr[nj] = *(const short8*)(Bs + (wn * 64 + nj * 16 + r) * 32 + g * 8);
    #pragma unroll
    for (int mi = 0; mi < 4; ++mi)
      #pragma unroll
      for (int nj = 0; nj < 4; ++nj)
        acc[mi][nj] = __builtin_amdgcn_mfma_f32_16x16x32_bf16(af[mi], bfr[nj], acc[mi][nj], 0, 0, 0);
    __syncthreads();
  }
  const int sb = sbase[e] + ib * 128;
  const int hc = ((bn + wn * 64) >> 1) + r;
  #pragma unroll
  for (int mi = 0; mi < 4; ++mi)
    #pragma unroll
    for (int reg = 0; reg < 4; ++reg) {
      int srow = sb + wm * 64 + mi * 16 + g * 4 + reg;
      #pragma unroll
      for (int p = 0; p < 2; ++p) {
        float a = acc[mi][2 * p][reg], b3 = acc[mi][2 * p + 1][reg];
        Cb[(size_t)srow * 512 + hc + p * 16] = f2bf((a / (1.f + __expf(-a))) * b3);
      }
    }
}

// ---------------- expert w2 GEMM + weighted atomic scatter ----------------
__global__ __launch_bounds__(256) void gemm_moe2(
    const unsigned short* __restrict__ Am, const unsigned short* __restrict__ W,
    float* __restrict__ out,
    const int* __restrict__ lists, const int* __restrict__ map, const int* __restrict__ sbase,
    const float* __restrict__ cw) {
  int mb = map[blockIdx.y];
  if (mb < 0) return;
  const int e = mb >> 16, ib = mb & 0xFFFF;
  __shared__ __align__(16) unsigned short As[128 * 32];
  __shared__ __align__(16) unsigned short Bs[128 * 32];
  const int tid = threadIdx.x, lane = tid & 63, wave = tid >> 6;
  const int wm = wave >> 1, wn = wave & 1;
  const int bn = blockIdx.x * 128;
  const int r = lane & 15, g = lane >> 4;

  f32x4 acc[4][4];
  #pragma unroll
  for (int i = 0; i < 4; ++i)
    #pragma unroll
    for (int j = 0; j < 4; ++j) acc[i][j] = (f32x4)0.f;

  const int rl0 = wave * 16 + (lane >> 2), rl1 = rl0 + 64;
  const int kc = (lane & 3) * 8;
  const int sb = sbase[e] + ib * 128;
  const unsigned short* Wb = W + (size_t)e * 512 * 1024;
  char* AsB = (char*)As; char* BsB = (char*)Bs;

  for (int k0 = 0; k0 < 512; k0 += 32) {
    GLD16(Am + (size_t)(sb + rl0) * 512 + k0 + kc, AsB + wave * 1024);
    GLD16(Am + (size_t)(sb + rl1) * 512 + k0 + kc, AsB + (wave + 4) * 1024);
    GLD16(Wb + (size_t)(bn + rl0) * 512 + k0 + kc, BsB + wave * 1024);
    GLD16(Wb + (size_t)(bn + rl1) * 512 + k0 + kc, BsB + (wave + 4) * 1024);
    __syncthreads();
    short8 af[4], bfr[4];
    #pragma unroll
    for (int mi = 0; mi < 4; ++mi)
      af[mi] = *(const short8*)(As + (wm * 64 + mi * 16 + r) * 32 + g * 8);
    #pragma unroll
    for (int nj = 0; nj < 4; ++nj)
      bfr[nj] = *(const short8*)(Bs + (wn * 64 + nj * 16 + r) * 32 + g * 8);
    #pragma unroll
    for (int mi = 0; mi < 4; ++mi)
      #pragma unroll
      for (int nj = 0; nj < 4; ++nj)
        acc[mi][nj] = __builtin_amdgcn_mfma_f32_16x16x32_bf16(af[mi], bfr[nj], acc[mi][nj], 0, 0, 0);
    __syncthreads();
  }
  const int ocol0 = bn + wn * 64 + r;
  #pragma unroll
  for (int mi = 0; mi < 4; ++mi)
    #pragma unroll
    for (int reg = 0; reg < 4; ++reg) {
      int orow = wm * 64 + mi * 16 + g * 4 + reg;
      int tok = lists[e * LSTR + ib * 128 + orow];
      if (tok >= 0) {
        float wt = cw[(size_t)tok * E_ + e];
        #pragma unroll
        for (int nj = 0; nj < 4; ++nj)
          atomicAdd(out + (size_t)tok * 1024 + ocol0 + nj * 16, acc[mi][nj][reg] * wt);
      }
    }
}

// ---------------- MFMA flash attention (rope-on-stage, exp2 softmax) ----------------
#define AQ 64
#define AK 32
#define VP 40
__global__ __launch_bounds__(256) void attn_mfma(
    const unsigned short* __restrict__ q,   // [NTOK][H][192] (rope NOT yet applied)
    const unsigned short* __restrict__ kv,  // [NTOK][H][256] (nope valid)
    const unsigned short* __restrict__ kr,  // [NTOK][64]
    const unsigned short* __restrict__ vt,  // [16][128][2048]
    const float* __restrict__ fcos, const float* __restrict__ fsin,
    unsigned short* __restrict__ y) {       // [NTOK][1024]
  __shared__ __align__(16) unsigned short Qs[AQ * 192];
  __shared__ __align__(16) unsigned short Ks[AK * 192];
  __shared__ __align__(16) unsigned short Vl[128 * VP];
  __shared__ __align__(16) unsigned short Ps[4 * 16 * VP];
  const int tid = threadIdx.x, lane = tid & 63, wave = tid >> 6;
  const int r = lane & 15, g = lane >> 4;
  const int bh = blockIdx.y, b = bh >> 3, h = bh & 7;
  const int qt = gridDim.x - 1 - blockIdx.x;   // LPT
  const int q0 = qt * AQ;
  const size_t bT = (size_t)b * T_;
  const unsigned short* vbase = vt + (size_t)bh * 128 * T_;
  char* QsB = (char*)Qs; char* KsB = (char*)Ks;

  // Q staging with fused RoPE (swizzled rows, pitch 384B)
  #pragma unroll
  for (int it = 0; it < 6; ++it) {
    int c = tid + it * 256;
    int row = c / 24, c8 = c % 24;
    short8 v = *(const short8*)(q + ((bT + q0 + row) * H_ + h) * 192 + c8 * 8);
    if (c8 >= 16) {
      int t = q0 + row;
      int ib = (c8 - 16) * 4;
      #pragma unroll
      for (int p = 0; p < 4; ++p) {
        float cc = fcos[t * 32 + ib + p], sn = fsin[t * 32 + ib + p];
        float x0 = bf2f((unsigned short)v[2 * p]), x1 = bf2f((unsigned short)v[2 * p + 1]);
        v[2 * p]     = (short)f2bf(x0 * cc - x1 * sn);
        v[2 * p + 1] = (short)f2bf(x0 * sn + x1 * cc);
      }
    }
    *(short8*)(QsB + ((row * 384 + c8 * 16) ^ ((row & 7) << 4))) = v;
  }

  float m_i[4], l_i[4];
  f32x4 o[8];
  #pragma unroll
  for (int i = 0; i < 4; ++i) { m_i[i] = -1e30f; l_i[i] = 0.f; }
  #pragma unroll
  for (int cb = 0; cb < 8; ++cb) o[cb] = (f32x4)0.f;

  const float scale2 = 0.07216878364870322f * 1.44269504088896f; // 1/sqrt(192)*log2e
  const int ntiles = q0 / AK + 2;

  // prefetch tile 0 (K and V) into registers
  short8 kreg[3], vreg[2];
  int krow[3], kcol[3];
  #pragma unroll
  for (int it = 0; it < 3; ++it) {
    int c = tid + it * 256;
    krow[it] = c / 24; kcol[it] = c % 24;
    kreg[it] = (kcol[it] < 16)
      ? *(const short8*)(kv + ((bT + krow[it]) * H_ + h) * 256 + kcol[it] * 8)
      : *(const short8*)(kr + (bT + krow[it]) * 64 + (kcol[it] - 16) * 8);
  }
  #pragma unroll
  for (int it = 0; it < 2; ++it) {
    int x = tid + it * 256;
    vreg[it] = *(const short8*)(vbase + (size_t)(x >> 2) * T_ + (x & 3) * 8);
  }

  for (int kt = 0; kt < ntiles; ++kt) {
    __syncthreads();
    #pragma unroll
    for (int it = 0; it < 3; ++it)
      *(short8*)(KsB + ((krow[it] * 384 + kcol[it] * 16) ^ ((krow[it] & 7) << 4))) = kreg[it];
    #pragma unroll
    for (int it = 0; it < 2; ++it) {
      int x = tid + it * 256;
      *(short8*)(Vl + (x >> 2) * VP + (x & 3) * 8) = vreg[it];
    }
    __syncthreads();

    if (kt + 1 < ntiles) {
      int k1 = (kt + 1) * AK;
      #pragma unroll
      for (int it = 0; it < 3; ++it)
        kreg[it] = (kcol[it] < 16)
          ? *(const short8*)(kv + ((bT + k1 + krow[it]) * H_ + h) * 256 + kcol[it] * 8)
          : *(const short8*)(kr + (bT + k1 + krow[it]) * 64 + (kcol[it] - 16) * 8);
      #pragma unroll
      for (int it = 0; it < 2; ++it) {
        int x = tid + it * 256;
        vreg[it] = *(const short8*)(vbase + (size_t)(x >> 2) * T_ + k1 + (x & 3) * 8);
      }
    }

    const int k0 = kt * AK;
    f32x4 sf0 = (f32x4)0.f, sf1 = (f32x4)0.f;
    {
      int qrow = wave * 16 + r;
      int qsw = (qrow & 7) << 4, ksw = (r & 7) << 4;
      __builtin_amdgcn_s_setprio(1);
      #pragma unroll
      for (int kk = 0; kk < 6; ++kk) {
        short8 aq = *(const short8*)(QsB + ((qrow * 384 + kk * 64 + g * 16) ^ qsw));
        short8 b0 = *(const short8*)(KsB + ((r * 384 + kk * 64 + g * 16) ^ ksw));
        short8 b1 = *(const short8*)(KsB + (((16 + r) * 384 + kk * 64 + g * 16) ^ ksw));
        sf0 = __builtin_amdgcn_mfma_f32_16x16x32_bf16(aq, b0, sf0, 0, 0, 0);
        sf1 = __builtin_amdgcn_mfma_f32_16x16x32_bf16(aq, b1, sf1, 0, 0, 0);
      }
      __builtin_amdgcn_s_setprio(0);
    }
    float fac[4];
    bool needs = false;
    #pragma unroll
    for (int reg = 0; reg < 4; ++reg) {
      float s0 = sf0[reg] * scale2;   // log2 domain
      float s1 = sf1[reg] * scale2;
      int qp = q0 + wave * 16 + g * 4 + reg;
      if (k0 + r > qp) s0 = -1e30f;
      if (k0 + 16 + r > qp) s1 = -1e30f;
      float mt = dppmax16(fmaxf(s0, s1));
      float fc = 1.f, mn = m_i[reg];
      if (mt > mn + 8.f) {            // defer-max (log2 units; P bounded by 256)
        mn = mt; fc = exp2f(m_i[reg] - mn); m_i[reg] = mn; needs = true;
      }
      float e0 = exp2f(s0 - mn), e1 = exp2f(s1 - mn);
      float rs = dppsum16(e0 + e1);
      l_i[reg] = l_i[reg] * fc + rs;
      fac[reg] = fc;
      __hip_bfloat162 pk = __float22bfloat162_rn(float2{e0, e1});
      unsigned u = *(unsigned*)&pk;
      int prow = g * 4 + reg;
      Ps[wave * 16 * VP + prow * VP + r] = (unsigned short)u;
      Ps[wave * 16 * VP + prow * VP + 16 + r] = (unsigned short)(u >> 16);
    }
    if (__any(needs)) {
      #pragma unroll
      for (int cb = 0; cb < 8; ++cb)
        #pragma unroll
        for (int reg = 0; reg < 4; ++reg) o[cb][reg] *= fac[reg];
    }
    short8 pa = *(const short8*)(Ps + wave * 16 * VP + r * VP + g * 8);
    __builtin_amdgcn_s_setprio(1);
    #pragma unroll
    for (int cb = 0; cb < 8; ++cb) {
      short8 vb = *(const short8*)(Vl + (cb * 16 + r) * VP + g * 8);
      o[cb] = __builtin_amdgcn_mfma_f32_16x16x32_bf16(pa, vb, o[cb], 0, 0, 0);
    }
    __builtin_amdgcn_s_setprio(0);
  }

  #pragma unroll
  for (int reg = 0; reg < 4; ++reg) {
    float inv = 1.f / l_i[reg];
    int nrow = q0 + wave * 16 + g * 4 + reg;
    size_t bas = (bT + nrow) * (size_t)D_ + h * VD_;
    #pragma unroll
    for (int cb = 0; cb < 8; ++cb)
      y[bas + cb * 16 + r] = f2bf(o[cb][reg] * inv);
  }
}

// ---------------- fused rms2 + gate (logits, softmax, top2) ----------------
__global__ __launch_bounds__(256) void rms2_gate(
    const float* __restrict__ xo, const float* __restrict__ rw, const float* __restrict__ gw,
    unsigned short* __restrict__ h2b, float* __restrict__ cw) {
  int row = blockIdx.x, tid = threadIdx.x;
  int lane = tid & 63, wv = tid >> 6;
  const float* xr = xo + (size_t)row * D_;
  float v[4]; float ss = 0.f;
  #pragma unroll
  for (int j = 0; j < 4; ++j) { v[j] = xr[tid + j * 256]; ss += v[j] * v[j]; }
  for (int o = 1; o < 64; o <<= 1) ss += __shfl_xor(ss, o);
  __shared__ float red[4];
  if (lane == 0) red[wv] = ss;
  __syncthreads();
  float inv = 1.f / sqrtf((red[0] + red[1] + red[2] + red[3]) / D_ + 1e-6f);
  float a[E_] = {0, 0, 0, 0, 0, 0, 0, 0};
  #pragma unroll
  for (int j = 0; j < 4; ++j) {
    int i = tid + j * 256;
    float hv = v[j] * inv * rw[i];
    h2b[(size_t)row * D_ + i] = f2bf(hv);
    const float* wr = gw + (size_t)i * E_;
    #pragma unroll
    for (int e = 0; e < E_; ++e) a[e] += hv * wr[e];
  }
  #pragma unroll
  for (int e = 0; e < E_; ++e) {
    float t = a[e];
    for (int o = 1; o < 64; o <<= 1) t += __shfl_xor(t, o);
    a[e] = t;
  }
  __shared__ float ga[4][E_];
  if (lane == 0)
    #pragma unroll
    for (int e = 0; e < E_; ++e) ga[wv][e] = a[e];
  __syncthreads();
  if (tid == 0) {
    float lg[E_];
    #pragma unroll
    for (int e = 0; e < E_; ++e) lg[e] = ga[0][e] + ga[1][e] + ga[2][e] + ga[3][e];
    float mx = lg[0];
    #pragma unroll
    for (int e = 1; e < E_; ++e) mx = fmaxf(mx, lg[e]);
    float sum = 0.f; float p[E_];
    #pragma unroll
    for (int e = 0; e < E_; ++e) { p[e] = __expf(lg[e] - mx); sum += p[e]; }
    float is = 1.f / sum;
    int i1 = 0; float b1 = p[0];
    #pragma unroll
    for (int e = 1; e < E_; ++e) if (p[e] > b1) { b1 = p[e]; i1 = e; }
    int i2 = -1; float b2 = -1.f;
    #pragma unroll
    for (int e = 0; e < E_; ++e) if (e != i1 && p[e] > b2) { b2 = p[e]; i2 = e; }
    #pragma unroll
    for (int e = 0; e < E_; ++e)
      cw[(size_t)row * E_ + e] = (e == i1) ? b1 * is : (e == i2 ? b2 * is : 0.f);
  }
}

// ---------------- MoE token compaction (ballot-based, deterministic) ----------------
__global__ __launch_bounds__(256) void moe_build(const float* __restrict__ cw,
                                                 int* __restrict__ lists, int* __restrict__ counts) {
  int e = blockIdx.x, tid = threadIdx.x;
  int lane = tid & 63, wv = tid >> 6;
  __shared__ int wsum[4];
  __shared__ int base;
  if (tid == 0) base = 0;
  __syncthreads();
  for (int c0 = 0; c0 < NTOK; c0 += 256) {
    int tok = c0 + tid;
    bool f = cw[(size_t)tok * E_ + e] > 0.f;
    unsigned long long m = __ballot(f);
    int pos = __popcll(m & ((1ull << lane) - 1ull));
    if (lane == 0) wsum[wv] = __popcll(m);
    __syncthreads();
    int woff = base;
    #pragma unroll
    for (int w = 0; w < 4; ++w) if (w < wv) woff += wsum[w];
    if (f) lists[e * LSTR + woff + pos] = tok;
    __syncthreads();
    if (tid == 0) base += wsum[0] + wsum[1] + wsum[2] + wsum[3];
    __syncthreads();
  }
  int cnt = base;
  int padded = (cnt + 127) & ~127;
  for (int i2 = cnt + tid; i2 < padded; i2 += 256) lists[e * LSTR + i2] = -1;
  if (tid == 0) { counts[e] = cnt; counts[8 + e] = padded >> 7; }
}

__global__ void moe_finalize(const int* __restrict__ counts, int* __restrict__ map,
                             int* __restrict__ sbase) {
  if (threadIdx.x == 0 && blockIdx.x == 0) {
    int cum = 0;
    for (int e = 0; e < E_; ++e) {
      sbase[e] = cum * 128;
      int nb = counts[8 + e];
      for (int i = 0; i < nb; ++i) map[cum + i] = (e << 16) | i;
      cum += nb;
    }
    for (; cum < MAXMB; ++cum) map[cum] = -1;
  }
}

extern "C" void kernel_launch(void* const* d_in, const int* in_sizes, int n_in,
                              void* d_out, int out_size, void* d_ws, size_t ws_size,
                              hipStream_t stream) {
  const float* x        = (const float*)d_in[0];
  const float* fcos     = (const float*)d_in[1];
  const float* fsin     = (const float*)d_in[2];
  const float* rmsn1_w  = (const float*)d_in[3];
  const float* rmsn2_w  = (const float*)d_in[4];
  const float* latent_w = (const float*)d_in[5];
  const float* q_norm_w = (const float*)d_in[6];
  const float* q_up_w   = (const float*)d_in[7];
  const float* kv_norm_w= (const float*)d_in[8];
  const float* kv_up_w  = (const float*)d_in[9];
  const float* c_proj_w = (const float*)d_in[10];
  const float* gate_w   = (const float*)d_in[11];
  const float* sh_w1    = (const float*)d_in[12];
  const float* sh_w2    = (const float*)d_in[13];
  const float* sh_w3    = (const float*)d_in[14];
  const float* e_w1     = (const float*)d_in[15];
  const float* e_w2     = (const float*)d_in[16];
  const float* e_w3     = (const float*)d_in[17];
  float* out = (float*)d_out;

  char* base = (char*)d_ws;
  size_t off = 0;
  auto take = [&](size_t bytes) { char* p = base + off; off += (bytes + 255) & ~(size_t)255; return p; };
  unsigned short* Wlat  = (unsigned short*)take((size_t)768 * 1024 * 2);
  unsigned short* Wqup  = (unsigned short*)take((size_t)1536 * 384 * 2);
  unsigned short* Wkv   = (unsigned short*)take((size_t)2048 * 256 * 2);
  unsigned short* Wcp   = (unsigned short*)take((size_t)1024 * 1024 * 2);
  unsigned short* Wsh13 = (unsigned short*)take((size_t)2048 * 1024 * 2);
  unsigned short* Wsh2  = (unsigned short*)take((size_t)1024 * 1024 * 2);
  unsigned short* Wew13 = (unsigned short*)take((size_t)8 * 1024 * 1024 * 2);
  unsigned short* Wew2  = (unsigned short*)take((size_t)8 * 1024 * 512 * 2);
  float* cw             = (float*)take((size_t)NTOK * E_ * 4);
  int* lists            = (int*)take((size_t)E_ * LSTR * 4);
  int* counts           = (int*)take(64 * 4);
  int* map              = (int*)take(MAXMB * 4);
  int* sbase            = (int*)take(E_ * 4);
  unsigned short* Vtg   = (unsigned short*)take((size_t)16 * 128 * T_ * 2);
  unsigned short* kr    = (unsigned short*)take((size_t)NTOK * 64 * 2);

  size_t actStart = off;
  size_t aoff = actStart;
  auto takeA = [&](size_t bytes) { char* p = base + aoff; aoff += (bytes + 255) & ~(size_t)255; return p; };
  unsigned short* h_bf = (unsigned short*)takeA((size_t)NTOK * 1024 * 2);
  unsigned short* lat  = (unsigned short*)takeA((size_t)NTOK * 768 * 2);
  unsigned short* qn   = (unsigned short*)takeA((size_t)NTOK * 384 * 2);
  unsigned short* kvn  = (unsigned short*)takeA((size_t)NTOK * 256 * 2);
  unsigned short* qq   = (unsigned short*)takeA((size_t)NTOK * 1536 * 2);
  unsigned short* kvb  = (unsigned short*)takeA((size_t)NTOK * 2048 * 2);
  unsigned short* y    = (unsigned short*)takeA((size_t)NTOK * 1024 * 2);

  size_t coff = actStart;
  auto takeC = [&](size_t bytes) { char* p = base + coff; coff += (bytes + 255) & ~(size_t)255; return p; };
  unsigned short* h2b  = (unsigned short*)takeC((size_t)NTOK * 1024 * 2);
  unsigned short* t1m  = (unsigned short*)takeC((size_t)NTOK * 1024 * 2);
  unsigned short* ehm  = (unsigned short*)takeC((size_t)9216 * 512 * 2);

  dim3 blk(256);

  // --- weight conversion ---
  transpose_f32_bf16<<<dim3(22, 32, 1), blk, 0, stream>>>(latent_w, Wlat, 1024, 704, 0, 0);
  transpose_f32_bf16<<<dim3(48, 12, 1), blk, 0, stream>>>(q_up_w, Wqup, 384, 1536, 0, 0);
  transpose_f32_bf16<<<dim3(64, 8, 1), blk, 0, stream>>>(kv_up_w, Wkv, 256, 2048, 0, 0);
  transpose_f32_bf16<<<dim3(32, 32, 1), blk, 0, stream>>>(c_proj_w, Wcp, 1024, 1024, 0, 0);
  transpose_f32_bf16<<<dim3(32, 32, 1), blk, 0, stream>>>(sh_w2, Wsh2, 1024, 1024, 0, 0);
  transpose_pair<<<dim3(32, 32, 2), blk, 0, stream>>>(sh_w1, sh_w3, Wsh13, 1024, 1024, 0, 0);
  transpose_pair<<<dim3(16, 32, 16), blk, 0, stream>>>(e_w1, e_w3, Wew13, 1024, 512,
      (size_t)1024 * 512, (size_t)1024 * 1024);
  transpose_f32_bf16<<<dim3(32, 16, 8), blk, 0, stream>>>(e_w2, Wew2, 512, 1024,
      (size_t)512 * 1024, (size_t)1024 * 512);

  rms_to_bf16<float><<<NTOK, blk, 0, stream>>>(x, D_, 0, rmsn1_w, h_bf, D_, D_);
  gemm_bf16<0><<<dim3(6, 32), blk, 0, stream>>>(h_bf, Wlat, lat, NTOK, 768, 1024, nullptr, nullptr);
  lat_post<<<NTOK, blk, 0, stream>>>(lat, q_norm_w, kv_norm_w, fcos, fsin, qn, kvn, kr);
  gemm_bf16<0><<<dim3(12, 32), blk, 0, stream>>>(qn, Wqup, qq, NTOK, 1536, 384, nullptr, nullptr);
  gemm_bf16<5><<<dim3(16, 32), blk, 0, stream>>>(kvn, Wkv, kvb, NTOK, 2048, 256, nullptr, Vtg);
  attn_mfma<<<dim3(T_ / AQ, B_ * H_), blk, 0, stream>>>(qq, kvb, kr, Vtg, fcos, fsin, y);
  gemm_bf16<1><<<dim3(8, 32), blk, 0, stream>>>(y, Wcp, out, NTOK, 1024, 1024, x, nullptr);
  rms2_gate<<<NTOK, blk, 0, stream>>>(out, rmsn2_w, gate_w, h2b, cw);
  moe_build<<<E_, blk, 0, stream>>>(cw, lists, counts);
  moe_finalize<<<1, 64, 0, stream>>>(counts, map, sbase);
  // shared expert (silu fused into w13 GEMM epilogue)
  gemm_bf16<4><<<dim3(16, 32), blk, 0, stream>>>(h2b, Wsh13, t1m, NTOK, 2048, 1024, nullptr, nullptr);
  gemm_bf16<2><<<dim3(8, 32), blk, 0, stream>>>(t1m, Wsh2, out, NTOK, 1024, 1024, nullptr, nullptr);
  // sparse experts (silu fused)
  gemm_moe13<<<dim3(8, MAXMB), blk, 0, stream>>>(h2b, Wew13, ehm, lists, map, sbase);
  gemm_moe2<<<dim3(8, MAXMB), blk, 0, stream>>>(ehm, Wew2, out, lists, map, sbase, cw);
}